// Round 1
// baseline (3164.886 us; speedup 1.0000x reference)
//
#include <hip/hip_runtime.h>

#define IN_F 128
#define HID  128
#define N_CLS 2

// ---------------------------------------------------------------------------
// Kernel 1: degree computation (float atomics; counts are exact integers)
// ---------------------------------------------------------------------------
__global__ void deg_kernel(const int* __restrict__ src, const int* __restrict__ dst,
                           float* __restrict__ deg_out, float* __restrict__ deg_in, int E) {
    int i = blockIdx.x * blockDim.x + threadIdx.x;
    if (i < E) {
        unsafeAtomicAdd(&deg_out[src[i]], 1.0f);
        unsafeAtomicAdd(&deg_in[dst[i]], 1.0f);
    }
}

// ---------------------------------------------------------------------------
// Kernel 2: deg -> deg^-0.5 in place (0 for zero-degree)
// ---------------------------------------------------------------------------
__global__ void ninv_kernel(float* __restrict__ a, float* __restrict__ b, int N) {
    int i = blockIdx.x * blockDim.x + threadIdx.x;
    if (i < N) {
        float x = a[i];
        a[i] = (x > 0.0f) ? rsqrtf(x) : 0.0f;
        float y = b[i];
        b[i] = (y > 0.0f) ? rsqrtf(y) : 0.0f;
    }
}

// ---------------------------------------------------------------------------
// Kernel 3: layer-1 edge scatter. agg1[dst] += in_feat[src] * ninv_out[src]
// One thread per (edge, float4-chunk): 32 threads/edge, float4 gather.
// ninv_out scaling fused here so h0 is never materialized.
// ---------------------------------------------------------------------------
__global__ void scatter1_kernel(const float* __restrict__ in_feat,
                                const int* __restrict__ src, const int* __restrict__ dst,
                                const float* __restrict__ ninv_out,
                                float* __restrict__ agg1, long total) {
    long i = (long)blockIdx.x * blockDim.x + threadIdx.x;
    if (i >= total) return;
    int f4 = (int)(i & 31);      // which float4 of the 128-dim row
    long e = i >> 5;
    int s = src[e];
    int d = dst[e];
    float no = ninv_out[s];
    float4 v = ((const float4*)in_feat)[(long)s * 32 + f4];
    float* base = &agg1[(long)d * IN_F + f4 * 4];
    unsafeAtomicAdd(base + 0, v.x * no);
    unsafeAtomicAdd(base + 1, v.y * no);
    unsafeAtomicAdd(base + 2, v.z * no);
    unsafeAtomicAdd(base + 3, v.w * no);
}

// ---------------------------------------------------------------------------
// Kernel 4: h2 = relu(agg1 @ W1 * ninv_in + b1) * ninv_out, written IN PLACE
// over agg1 (each block owns its 32 rows entirely, reads staged to LDS first).
// LDS: W1 64KB + x-tile 16KB = 80KB -> 2 blocks/CU. 4x4 register blocking.
// ---------------------------------------------------------------------------
#define MM1_ROWS 32
__global__ __launch_bounds__(256, 2)
void mm1_kernel(float* __restrict__ B, const float* __restrict__ W1,
                const float* __restrict__ b1, const float* __restrict__ ninv_in,
                const float* __restrict__ ninv_out, int N) {
    __shared__ float ws[IN_F * HID];          // [k][c], 64KB
    __shared__ float xs[MM1_ROWS][IN_F];      // 16KB
    int tid = threadIdx.x;
    int row0 = blockIdx.x * MM1_ROWS;

    // stage W1 (coalesced float4)
    float4* ws4 = (float4*)ws;
    const float4* w14 = (const float4*)W1;
#pragma unroll
    for (int j = 0; j < 16; ++j) ws4[j * 256 + tid] = w14[j * 256 + tid];

    // stage x tile (coalesced float4), zero-pad rows past N
    float4* xs4 = (float4*)&xs[0][0];
    const float4* B4 = (const float4*)B;
#pragma unroll
    for (int j = 0; j < 4; ++j) {
        int idx = j * 256 + tid;              // float4 index in 32x32 tile
        int r = idx >> 5, k4 = idx & 31;
        int grow = row0 + r;
        xs4[idx] = (grow < N) ? B4[(long)grow * 32 + k4] : make_float4(0.f, 0.f, 0.f, 0.f);
    }
    __syncthreads();

    int ct = tid & 31;   // col group: cols 4*ct .. 4*ct+3
    int rt = tid >> 5;   // row group: rows 4*rt .. 4*rt+3
    float acc[4][4] = {};
#pragma unroll 4
    for (int k = 0; k < IN_F; ++k) {
        float4 w = ws4[k * 32 + ct];
        float x0 = xs[4 * rt + 0][k];
        float x1 = xs[4 * rt + 1][k];
        float x2 = xs[4 * rt + 2][k];
        float x3 = xs[4 * rt + 3][k];
        acc[0][0] += x0 * w.x; acc[0][1] += x0 * w.y; acc[0][2] += x0 * w.z; acc[0][3] += x0 * w.w;
        acc[1][0] += x1 * w.x; acc[1][1] += x1 * w.y; acc[1][2] += x1 * w.z; acc[1][3] += x1 * w.w;
        acc[2][0] += x2 * w.x; acc[2][1] += x2 * w.y; acc[2][2] += x2 * w.z; acc[2][3] += x2 * w.w;
        acc[3][0] += x3 * w.x; acc[3][1] += x3 * w.y; acc[3][2] += x3 * w.z; acc[3][3] += x3 * w.w;
    }

    // epilogue: bias + relu + ninv_in, then pre-scale by ninv_out for layer 2
    float4* Bout4 = (float4*)B;
#pragma unroll
    for (int i = 0; i < 4; ++i) {
        int grow = row0 + 4 * rt + i;
        if (grow >= N) continue;
        float ni = ninv_in[grow];
        float no = ninv_out[grow];
        float4 o;
        o.x = fmaxf(acc[i][0] * ni + b1[4 * ct + 0], 0.f) * no;
        o.y = fmaxf(acc[i][1] * ni + b1[4 * ct + 1], 0.f) * no;
        o.z = fmaxf(acc[i][2] * ni + b1[4 * ct + 2], 0.f) * no;
        o.w = fmaxf(acc[i][3] * ni + b1[4 * ct + 3], 0.f) * no;
        Bout4[(long)grow * 32 + ct] = o;
    }
}

// ---------------------------------------------------------------------------
// Kernel 5: t = h2 @ W2  (N x 2). 16 threads per row, shfl reduction.
// ---------------------------------------------------------------------------
__global__ void mm2_kernel(const float* __restrict__ B, const float* __restrict__ W2,
                           float* __restrict__ t, int N) {
    int gtid = blockIdx.x * blockDim.x + threadIdx.x;
    int row = gtid >> 4;
    int lane = gtid & 15;
    if (row >= N) return;
    float p0 = 0.f, p1 = 0.f;
#pragma unroll
    for (int j = 0; j < 8; ++j) {
        int k = lane + 16 * j;
        float x = B[(long)row * IN_F + k];
        p0 += x * W2[k * 2 + 0];
        p1 += x * W2[k * 2 + 1];
    }
#pragma unroll
    for (int o = 8; o >= 1; o >>= 1) {
        p0 += __shfl_xor(p0, o, 16);
        p1 += __shfl_xor(p1, o, 16);
    }
    if (lane == 0) {
        t[row * 2 + 0] = p0;
        t[row * 2 + 1] = p1;
    }
}

// ---------------------------------------------------------------------------
// Kernel 6: layer-2 edge scatter. agg2[dst] += t[src]  (2 floats/edge)
// ---------------------------------------------------------------------------
__global__ void scatter2_kernel(const float* __restrict__ t,
                                const int* __restrict__ src, const int* __restrict__ dst,
                                float* __restrict__ agg2, int E) {
    int i = blockIdx.x * blockDim.x + threadIdx.x;
    if (i >= E) return;
    int s = src[i];
    int d = dst[i];
    float2 v = ((const float2*)t)[s];
    unsafeAtomicAdd(&agg2[d * 2 + 0], v.x);
    unsafeAtomicAdd(&agg2[d * 2 + 1], v.y);
}

// ---------------------------------------------------------------------------
// Kernel 7: out = agg2 * ninv_in + b2
// ---------------------------------------------------------------------------
__global__ void final_kernel(const float* __restrict__ agg2, const float* __restrict__ ninv_in,
                             const float* __restrict__ b2, float* __restrict__ out, int N) {
    int i = blockIdx.x * blockDim.x + threadIdx.x;
    if (i >= N) return;
    float ni = ninv_in[i];
    float2 v = ((const float2*)agg2)[i];
    float2 o;
    o.x = v.x * ni + b2[0];
    o.y = v.y * ni + b2[1];
    ((float2*)out)[i] = o;
}

// ---------------------------------------------------------------------------
extern "C" void kernel_launch(void* const* d_in, const int* in_sizes, int n_in,
                              void* d_out, int out_size, void* d_ws, size_t ws_size,
                              hipStream_t stream) {
    const float* in_feat = (const float*)d_in[0];
    const float* W1      = (const float*)d_in[1];
    const float* b1      = (const float*)d_in[2];
    const float* W2      = (const float*)d_in[3];
    const float* b2      = (const float*)d_in[4];
    const int*   src     = (const int*)d_in[5];
    const int*   dst     = (const int*)d_in[6];
    int N = in_sizes[0] / IN_F;
    int E = in_sizes[5];

    // workspace layout (floats):
    //   [0, 128N)       B: agg1, then overwritten in-place with h2
    //   [128N, 129N)    deg_out -> ninv_out
    //   [129N, 130N)    deg_in  -> ninv_in
    //   [130N, 132N)    agg2
    //   [132N, 134N)    t  (no zero-init needed; fully written by mm2)
    float* ws       = (float*)d_ws;
    float* B        = ws;
    float* ninv_out = ws + (size_t)128 * N;
    float* ninv_in  = ninv_out + N;
    float* agg2     = ninv_in + N;
    float* t        = agg2 + (size_t)2 * N;

    // zero B + deg_out + deg_in + agg2 in one shot (ws is poisoned 0xAA)
    hipMemsetAsync(ws, 0, (size_t)132 * N * sizeof(float), stream);

    deg_kernel<<<(E + 255) / 256, 256, 0, stream>>>(src, dst, ninv_out, ninv_in, E);
    ninv_kernel<<<(N + 255) / 256, 256, 0, stream>>>(ninv_out, ninv_in, N);

    long total1 = (long)E * 32;  // 32 float4-chunks per edge
    scatter1_kernel<<<(int)((total1 + 255) / 256), 256, 0, stream>>>(
        in_feat, src, dst, ninv_out, B, total1);

    mm1_kernel<<<(N + MM1_ROWS - 1) / MM1_ROWS, 256, 0, stream>>>(
        B, W1, b1, ninv_in, ninv_out, N);

    mm2_kernel<<<((N * 16) + 255) / 256, 256, 0, stream>>>(B, W2, t, N);

    scatter2_kernel<<<(E + 255) / 256, 256, 0, stream>>>(t, src, dst, agg2, E);

    final_kernel<<<(N + 255) / 256, 256, 0, stream>>>(agg2, ninv_in, b2, (float*)d_out, N);
}

// Round 2
// 573.958 us; speedup vs baseline: 5.5141x; 5.5141x over previous
//
#include <hip/hip_runtime.h>

#define IN_F 128
#define HID  128
#define SCAN_CHUNK 2048   // 256 threads x 8 elements

// ---------------------------------------------------------------------------
// Degrees (int atomics)
// ---------------------------------------------------------------------------
__global__ void deg_kernel(const int* __restrict__ src, const int* __restrict__ dst,
                           int* __restrict__ deg_out, int* __restrict__ deg_in, int E) {
    int i = blockIdx.x * blockDim.x + threadIdx.x;
    if (i < E) {
        atomicAdd(&deg_out[src[i]], 1);
        atomicAdd(&deg_in[dst[i]], 1);
    }
}

// deg -> deg^-0.5 (0 for zero degree), int in, float out
__global__ void ninv_kernel(const int* __restrict__ dego, const int* __restrict__ degi,
                            float* __restrict__ no, float* __restrict__ ni, int N) {
    int i = blockIdx.x * blockDim.x + threadIdx.x;
    if (i < N) {
        int a = dego[i];
        no[i] = (a > 0) ? rsqrtf((float)a) : 0.0f;
        int b = degi[i];
        ni[i] = (b > 0) ? rsqrtf((float)b) : 0.0f;
    }
}

// ---------------------------------------------------------------------------
// 3-kernel exclusive scan of deg_in -> row_ptr (CSR by dst)
// ---------------------------------------------------------------------------
__global__ void scan1_kernel(const int* __restrict__ deg, int* __restrict__ excl,
                             int* __restrict__ blockSums, int N) {
    __shared__ int sd[256];
    int tid = threadIdx.x;
    long base = (long)blockIdx.x * SCAN_CHUNK + tid * 8;
    int v[8]; int sum = 0;
#pragma unroll
    for (int j = 0; j < 8; ++j) {
        long idx = base + j;
        int x = (idx < N) ? deg[idx] : 0;
        v[j] = x; sum += x;
    }
    sd[tid] = sum; __syncthreads();
    for (int off = 1; off < 256; off <<= 1) {
        int t = (tid >= off) ? sd[tid - off] : 0;
        __syncthreads();
        sd[tid] += t;
        __syncthreads();
    }
    if (tid == 255) blockSums[blockIdx.x] = sd[255];
    int run = sd[tid] - sum;   // exclusive prefix of this thread's group
#pragma unroll
    for (int j = 0; j < 8; ++j) {
        long idx = base + j;
        if (idx < N) excl[idx] = run;
        run += v[j];
    }
}

__global__ void scan2_kernel(int* __restrict__ blockSums, int nb) {
    __shared__ int sd[256];
    int tid = threadIdx.x;
    int x = (tid < nb) ? blockSums[tid] : 0;
    sd[tid] = x; __syncthreads();
    for (int off = 1; off < 256; off <<= 1) {
        int t = (tid >= off) ? sd[tid - off] : 0;
        __syncthreads();
        sd[tid] += t;
        __syncthreads();
    }
    if (tid < nb) blockSums[tid] = sd[tid] - x;  // exclusive
}

// excl (+cursor, same buffer updated in place) + row_ptr
__global__ void scan3_kernel(int* __restrict__ excl_cursor, const int* __restrict__ blockSums,
                             int* __restrict__ row_ptr, int N, int E) {
    int i = blockIdx.x * blockDim.x + threadIdx.x;
    if (i < N) {
        int v = excl_cursor[i] + blockSums[i / SCAN_CHUNK];
        row_ptr[i] = v;
        excl_cursor[i] = v;   // becomes the fill cursor
    }
    if (i == 0) row_ptr[N] = E;
}

// bucket-fill: eidx sorted by dst holds src indices
__global__ void fill_kernel(const int* __restrict__ src, const int* __restrict__ dst,
                            int* __restrict__ cursor, int* __restrict__ eidx, int E) {
    int i = blockIdx.x * blockDim.x + threadIdx.x;
    if (i < E) {
        int pos = atomicAdd(&cursor[dst[i]], 1);
        eidx[pos] = src[i];
    }
}

// ---------------------------------------------------------------------------
// Layer-1 aggregation: one WAVE per node, lane owns a float2 of the row.
// B[d] = sum_{e: dst=d} in_feat[src_e] * ninv_out[src_e]   (no atomics)
// ---------------------------------------------------------------------------
__global__ __launch_bounds__(256)
void agg1_kernel(const float* __restrict__ in_feat, const int* __restrict__ row_ptr,
                 const int* __restrict__ eidx, const float* __restrict__ ninv_out,
                 float* __restrict__ B, int N) {
    int wave = threadIdx.x >> 6;
    int lane = threadIdx.x & 63;
    int d = blockIdx.x * 4 + wave;
    if (d >= N) return;
    int beg = row_ptr[d], end = row_ptr[d + 1];
    const float2* f2 = (const float2*)in_feat;
    float2 acc = make_float2(0.f, 0.f);
    int j = beg;
    for (; j + 1 < end; j += 2) {      // 2 outstanding gathers
        int s0 = eidx[j], s1 = eidx[j + 1];
        float n0 = ninv_out[s0], n1 = ninv_out[s1];
        float2 v0 = f2[(long)s0 * 64 + lane];
        float2 v1 = f2[(long)s1 * 64 + lane];
        acc.x += v0.x * n0; acc.y += v0.y * n0;
        acc.x += v1.x * n1; acc.y += v1.y * n1;
    }
    if (j < end) {
        int s = eidx[j];
        float n = ninv_out[s];
        float2 v = f2[(long)s * 64 + lane];
        acc.x += v.x * n; acc.y += v.y * n;
    }
    ((float2*)B)[(long)d * 64 + lane] = acc;
}

// ---------------------------------------------------------------------------
// h2 = relu(B @ W1 * ninv_in + b1) * ninv_out, IN PLACE over B.
// ---------------------------------------------------------------------------
#define MM1_ROWS 32
__global__ __launch_bounds__(256, 2)
void mm1_kernel(float* __restrict__ B, const float* __restrict__ W1,
                const float* __restrict__ b1, const float* __restrict__ ninv_in,
                const float* __restrict__ ninv_out, int N) {
    __shared__ float ws[IN_F * HID];          // [k][c], 64KB
    __shared__ float xs[MM1_ROWS][IN_F];      // 16KB
    int tid = threadIdx.x;
    int row0 = blockIdx.x * MM1_ROWS;

    float4* ws4 = (float4*)ws;
    const float4* w14 = (const float4*)W1;
#pragma unroll
    for (int j = 0; j < 16; ++j) ws4[j * 256 + tid] = w14[j * 256 + tid];

    float4* xs4 = (float4*)&xs[0][0];
    const float4* B4 = (const float4*)B;
#pragma unroll
    for (int j = 0; j < 4; ++j) {
        int idx = j * 256 + tid;
        int r = idx >> 5, k4 = idx & 31;
        int grow = row0 + r;
        xs4[idx] = (grow < N) ? B4[(long)grow * 32 + k4] : make_float4(0.f, 0.f, 0.f, 0.f);
    }
    __syncthreads();

    int ct = tid & 31;
    int rt = tid >> 5;
    float acc[4][4] = {};
#pragma unroll 4
    for (int k = 0; k < IN_F; ++k) {
        float4 w = ws4[k * 32 + ct];
        float x0 = xs[4 * rt + 0][k];
        float x1 = xs[4 * rt + 1][k];
        float x2 = xs[4 * rt + 2][k];
        float x3 = xs[4 * rt + 3][k];
        acc[0][0] += x0 * w.x; acc[0][1] += x0 * w.y; acc[0][2] += x0 * w.z; acc[0][3] += x0 * w.w;
        acc[1][0] += x1 * w.x; acc[1][1] += x1 * w.y; acc[1][2] += x1 * w.z; acc[1][3] += x1 * w.w;
        acc[2][0] += x2 * w.x; acc[2][1] += x2 * w.y; acc[2][2] += x2 * w.z; acc[2][3] += x2 * w.w;
        acc[3][0] += x3 * w.x; acc[3][1] += x3 * w.y; acc[3][2] += x3 * w.z; acc[3][3] += x3 * w.w;
    }

    float4* Bout4 = (float4*)B;
#pragma unroll
    for (int i = 0; i < 4; ++i) {
        int grow = row0 + 4 * rt + i;
        if (grow >= N) continue;
        float ni = ninv_in[grow];
        float no = ninv_out[grow];
        float4 o;
        o.x = fmaxf(acc[i][0] * ni + b1[4 * ct + 0], 0.f) * no;
        o.y = fmaxf(acc[i][1] * ni + b1[4 * ct + 1], 0.f) * no;
        o.z = fmaxf(acc[i][2] * ni + b1[4 * ct + 2], 0.f) * no;
        o.w = fmaxf(acc[i][3] * ni + b1[4 * ct + 3], 0.f) * no;
        Bout4[(long)grow * 32 + ct] = o;
    }
}

// ---------------------------------------------------------------------------
// t = h2 @ W2  (N x 2). 16 threads per row.
// ---------------------------------------------------------------------------
__global__ void mm2_kernel(const float* __restrict__ B, const float* __restrict__ W2,
                           float* __restrict__ t, int N) {
    int gtid = blockIdx.x * blockDim.x + threadIdx.x;
    int row = gtid >> 4;
    int lane = gtid & 15;
    if (row >= N) return;
    float p0 = 0.f, p1 = 0.f;
#pragma unroll
    for (int j = 0; j < 8; ++j) {
        int k = lane + 16 * j;
        float x = B[(long)row * IN_F + k];
        p0 += x * W2[k * 2 + 0];
        p1 += x * W2[k * 2 + 1];
    }
#pragma unroll
    for (int o = 8; o >= 1; o >>= 1) {
        p0 += __shfl_xor(p0, o, 16);
        p1 += __shfl_xor(p1, o, 16);
    }
    if (lane == 0) {
        t[row * 2 + 0] = p0;
        t[row * 2 + 1] = p1;
    }
}

// ---------------------------------------------------------------------------
// Layer-2 CSR gather fused with epilogue: out[d] = (sum t[src]) * ninv_in + b2
// ---------------------------------------------------------------------------
__global__ void final2_kernel(const float* __restrict__ t, const int* __restrict__ row_ptr,
                              const int* __restrict__ eidx, const float* __restrict__ ninv_in,
                              const float* __restrict__ b2, float* __restrict__ out, int N) {
    int i = blockIdx.x * blockDim.x + threadIdx.x;
    if (i >= N) return;
    int beg = row_ptr[i], end = row_ptr[i + 1];
    const float2* t2 = (const float2*)t;
    float ax = 0.f, ay = 0.f;
    for (int j = beg; j < end; ++j) {
        float2 v = t2[eidx[j]];
        ax += v.x; ay += v.y;
    }
    float ni = ninv_in[i];
    float2 o;
    o.x = ax * ni + b2[0];
    o.y = ay * ni + b2[1];
    ((float2*)out)[i] = o;
}

// ---------------------------------------------------------------------------
extern "C" void kernel_launch(void* const* d_in, const int* in_sizes, int n_in,
                              void* d_out, int out_size, void* d_ws, size_t ws_size,
                              hipStream_t stream) {
    const float* in_feat = (const float*)d_in[0];
    const float* W1      = (const float*)d_in[1];
    const float* b1      = (const float*)d_in[2];
    const float* W2      = (const float*)d_in[3];
    const float* b2      = (const float*)d_in[4];
    const int*   src     = (const int*)d_in[5];
    const int*   dst     = (const int*)d_in[6];
    int N = in_sizes[0] / IN_F;
    int E = in_sizes[5];

    // workspace layout
    float* ws        = (float*)d_ws;
    float* B         = ws;                             // 128N floats
    float* ninv_out  = ws + (size_t)128 * N;           // N
    float* ninv_in   = ninv_out + N;                   // N
    float* t         = ninv_in + N;                    // 2N
    int*   deg_out_i = (int*)(t + (size_t)2 * N);      // N
    int*   deg_in_i  = deg_out_i + N;                  // N
    int*   excl_cur  = deg_in_i + N;                   // N (excl scan, then cursor)
    int*   row_ptr   = excl_cur + N;                   // N+1
    int*   blockSums = row_ptr + N + 1;                // 256
    int*   eidx      = blockSums + 256;                // E

    // zero only the degree histograms
    hipMemsetAsync(deg_out_i, 0, (size_t)2 * N * sizeof(int), stream);

    deg_kernel<<<(E + 255) / 256, 256, 0, stream>>>(src, dst, deg_out_i, deg_in_i, E);
    ninv_kernel<<<(N + 255) / 256, 256, 0, stream>>>(deg_out_i, deg_in_i, ninv_out, ninv_in, N);

    int nb = (N + SCAN_CHUNK - 1) / SCAN_CHUNK;
    scan1_kernel<<<nb, 256, 0, stream>>>(deg_in_i, excl_cur, blockSums, N);
    scan2_kernel<<<1, 256, 0, stream>>>(blockSums, nb);
    scan3_kernel<<<(N + 255) / 256, 256, 0, stream>>>(excl_cur, blockSums, row_ptr, N, E);
    fill_kernel<<<(E + 255) / 256, 256, 0, stream>>>(src, dst, excl_cur, eidx, E);

    agg1_kernel<<<(N + 3) / 4, 256, 0, stream>>>(in_feat, row_ptr, eidx, ninv_out, B, N);

    mm1_kernel<<<(N + MM1_ROWS - 1) / MM1_ROWS, 256, 0, stream>>>(
        B, W1, b1, ninv_in, ninv_out, N);

    mm2_kernel<<<((N * 16) + 255) / 256, 256, 0, stream>>>(B, W2, t, N);

    final2_kernel<<<(N + 255) / 256, 256, 0, stream>>>(
        t, row_ptr, eidx, ninv_in, b2, (float*)d_out, N);
}

// Round 3
// 547.050 us; speedup vs baseline: 5.7854x; 1.0492x over previous
//
#include <hip/hip_runtime.h>

#define IN_F 128
#define HID  128
#define SCAN_CHUNK 2048   // 256 threads x 8 elements

// ---------------------------------------------------------------------------
// Degrees (int atomics)
// ---------------------------------------------------------------------------
__global__ void deg_kernel(const int* __restrict__ src, const int* __restrict__ dst,
                           int* __restrict__ deg_out, int* __restrict__ deg_in, int E) {
    int i = blockIdx.x * blockDim.x + threadIdx.x;
    if (i < E) {
        atomicAdd(&deg_out[src[i]], 1);
        atomicAdd(&deg_in[dst[i]], 1);
    }
}

// deg -> deg^-0.5 (0 for zero degree)
__global__ void ninv_kernel(const int* __restrict__ dego, const int* __restrict__ degi,
                            float* __restrict__ no, float* __restrict__ ni, int N) {
    int i = blockIdx.x * blockDim.x + threadIdx.x;
    if (i < N) {
        int a = dego[i];
        no[i] = (a > 0) ? rsqrtf((float)a) : 0.0f;
        int b = degi[i];
        ni[i] = (b > 0) ? rsqrtf((float)b) : 0.0f;
    }
}

// ---------------------------------------------------------------------------
// 3-kernel exclusive scan of deg_in -> row_ptr (CSR by dst)
// ---------------------------------------------------------------------------
__global__ void scan1_kernel(const int* __restrict__ deg, int* __restrict__ excl,
                             int* __restrict__ blockSums, int N) {
    __shared__ int sd[256];
    int tid = threadIdx.x;
    long base = (long)blockIdx.x * SCAN_CHUNK + tid * 8;
    int v[8]; int sum = 0;
#pragma unroll
    for (int j = 0; j < 8; ++j) {
        long idx = base + j;
        int x = (idx < N) ? deg[idx] : 0;
        v[j] = x; sum += x;
    }
    sd[tid] = sum; __syncthreads();
    for (int off = 1; off < 256; off <<= 1) {
        int t = (tid >= off) ? sd[tid - off] : 0;
        __syncthreads();
        sd[tid] += t;
        __syncthreads();
    }
    if (tid == 255) blockSums[blockIdx.x] = sd[255];
    int run = sd[tid] - sum;
#pragma unroll
    for (int j = 0; j < 8; ++j) {
        long idx = base + j;
        if (idx < N) excl[idx] = run;
        run += v[j];
    }
}

__global__ void scan2_kernel(int* __restrict__ blockSums, int nb) {
    __shared__ int sd[256];
    int tid = threadIdx.x;
    int x = (tid < nb) ? blockSums[tid] : 0;
    sd[tid] = x; __syncthreads();
    for (int off = 1; off < 256; off <<= 1) {
        int t = (tid >= off) ? sd[tid - off] : 0;
        __syncthreads();
        sd[tid] += t;
        __syncthreads();
    }
    if (tid < nb) blockSums[tid] = sd[tid] - x;
}

__global__ void scan3_kernel(int* __restrict__ excl_cursor, const int* __restrict__ blockSums,
                             int* __restrict__ row_ptr, int N, int E) {
    int i = blockIdx.x * blockDim.x + threadIdx.x;
    if (i < N) {
        int v = excl_cursor[i] + blockSums[i / SCAN_CHUNK];
        row_ptr[i] = v;
        excl_cursor[i] = v;
    }
    if (i == 0) row_ptr[N] = E;
}

__global__ void fill_kernel(const int* __restrict__ src, const int* __restrict__ dst,
                            int* __restrict__ cursor, int* __restrict__ eidx, int E) {
    int i = blockIdx.x * blockDim.x + threadIdx.x;
    if (i < E) {
        int pos = atomicAdd(&cursor[dst[i]], 1);
        eidx[pos] = src[i];
    }
}

// ---------------------------------------------------------------------------
// Layer-1 aggregation: one WAVE per node, lane owns a float2 of the row.
// 8-deep edge unroll -> 16 outstanding vmem per wave (latency hiding).
// ---------------------------------------------------------------------------
__global__ __launch_bounds__(256)
void agg1_kernel(const float* __restrict__ in_feat, const int* __restrict__ row_ptr,
                 const int* __restrict__ eidx, const float* __restrict__ ninv_out,
                 float* __restrict__ B, int N) {
    int wave = threadIdx.x >> 6;
    int lane = threadIdx.x & 63;
    int d = blockIdx.x * 4 + wave;
    if (d >= N) return;
    int beg = row_ptr[d], end = row_ptr[d + 1];
    const float2* f2 = (const float2*)in_feat;
    float2 acc = make_float2(0.f, 0.f);
    int j = beg;
    for (; j + 8 <= end; j += 8) {
        int s0 = eidx[j+0], s1 = eidx[j+1], s2 = eidx[j+2], s3 = eidx[j+3];
        int s4 = eidx[j+4], s5 = eidx[j+5], s6 = eidx[j+6], s7 = eidx[j+7];
        float n0 = ninv_out[s0], n1 = ninv_out[s1], n2 = ninv_out[s2], n3 = ninv_out[s3];
        float n4 = ninv_out[s4], n5 = ninv_out[s5], n6 = ninv_out[s6], n7 = ninv_out[s7];
        float2 v0 = f2[(long)s0*64+lane], v1 = f2[(long)s1*64+lane];
        float2 v2 = f2[(long)s2*64+lane], v3 = f2[(long)s3*64+lane];
        float2 v4 = f2[(long)s4*64+lane], v5 = f2[(long)s5*64+lane];
        float2 v6 = f2[(long)s6*64+lane], v7 = f2[(long)s7*64+lane];
        acc.x += v0.x*n0 + v1.x*n1 + v2.x*n2 + v3.x*n3 + v4.x*n4 + v5.x*n5 + v6.x*n6 + v7.x*n7;
        acc.y += v0.y*n0 + v1.y*n1 + v2.y*n2 + v3.y*n3 + v4.y*n4 + v5.y*n5 + v6.y*n6 + v7.y*n7;
    }
    for (; j + 2 <= end; j += 2) {
        int s0 = eidx[j], s1 = eidx[j+1];
        float n0 = ninv_out[s0], n1 = ninv_out[s1];
        float2 v0 = f2[(long)s0*64+lane], v1 = f2[(long)s1*64+lane];
        acc.x += v0.x*n0 + v1.x*n1;
        acc.y += v0.y*n0 + v1.y*n1;
    }
    if (j < end) {
        int s = eidx[j];
        float n = ninv_out[s];
        float2 v = f2[(long)s*64+lane];
        acc.x += v.x*n; acc.y += v.y*n;
    }
    ((float2*)B)[(long)d*64 + lane] = acc;
}

// ---------------------------------------------------------------------------
// Fused mm1+mm2: t[row] = ninv_out[row] * (relu(B[row]@W1 * ninv_in + b1) @ W2)
// h2 stays in registers and is never written. k-vectorized inner loop:
// per iter 8x ds_read_b128 + 64 FMA (VALU-bound).
// ---------------------------------------------------------------------------
#define MM1_ROWS 32
__global__ __launch_bounds__(256, 2)
void mm1_kernel(const float* __restrict__ B, const float* __restrict__ W1,
                const float* __restrict__ b1, const float* __restrict__ ninv_in,
                const float* __restrict__ ninv_out, const float* __restrict__ W2,
                float* __restrict__ t, int N) {
    __shared__ float ws[IN_F * HID];          // [k][c], 64KB
    __shared__ float xs[MM1_ROWS * IN_F];     // 16KB
    int tid = threadIdx.x;
    int row0 = blockIdx.x * MM1_ROWS;

    float4* ws4 = (float4*)ws;
    const float4* w14 = (const float4*)W1;
#pragma unroll
    for (int j = 0; j < 16; ++j) ws4[j * 256 + tid] = w14[j * 256 + tid];

    float4* xs4 = (float4*)xs;
    const float4* B4 = (const float4*)B;
#pragma unroll
    for (int j = 0; j < 4; ++j) {
        int idx = j * 256 + tid;
        int r = idx >> 5, k4 = idx & 31;
        int grow = row0 + r;
        xs4[idx] = (grow < N) ? B4[(long)grow * 32 + k4] : make_float4(0.f, 0.f, 0.f, 0.f);
    }

    int ct = tid & 31;
    int rt = tid >> 5;
    // per-thread W2 slice (k = 4*ct+q), and bias slice
    const float2* W2v = (const float2*)W2;
    float2 w2q[4];
#pragma unroll
    for (int q = 0; q < 4; ++q) w2q[q] = W2v[4 * ct + q];
    float4 b1v = ((const float4*)b1)[ct];
    __syncthreads();

    float4 acc[4];
#pragma unroll
    for (int i = 0; i < 4; ++i) acc[i] = make_float4(0.f, 0.f, 0.f, 0.f);

#pragma unroll 8
    for (int k4 = 0; k4 < 32; ++k4) {
        float4 wa = ws4[(4 * k4 + 0) * 32 + ct];
        float4 wb = ws4[(4 * k4 + 1) * 32 + ct];
        float4 wc = ws4[(4 * k4 + 2) * 32 + ct];
        float4 wd = ws4[(4 * k4 + 3) * 32 + ct];
#pragma unroll
        for (int i = 0; i < 4; ++i) {
            float4 x = xs4[(4 * rt + i) * 32 + k4];
            acc[i].x += x.x * wa.x + x.y * wb.x + x.z * wc.x + x.w * wd.x;
            acc[i].y += x.x * wa.y + x.y * wb.y + x.z * wc.y + x.w * wd.y;
            acc[i].z += x.x * wa.z + x.y * wb.z + x.z * wc.z + x.w * wd.z;
            acc[i].w += x.x * wa.w + x.y * wb.w + x.z * wc.w + x.w * wd.w;
        }
    }

    // epilogue: h2 = relu(acc*ni + b1); t = no * (h2 @ W2), width-32 reduce
#pragma unroll
    for (int i = 0; i < 4; ++i) {
        int grow = row0 + 4 * rt + i;
        if (grow >= N) continue;
        float ni = ninv_in[grow];
        float no = ninv_out[grow];
        float4 o;
        o.x = fmaxf(acc[i].x * ni + b1v.x, 0.f);
        o.y = fmaxf(acc[i].y * ni + b1v.y, 0.f);
        o.z = fmaxf(acc[i].z * ni + b1v.z, 0.f);
        o.w = fmaxf(acc[i].w * ni + b1v.w, 0.f);
        float p0 = o.x * w2q[0].x + o.y * w2q[1].x + o.z * w2q[2].x + o.w * w2q[3].x;
        float p1 = o.x * w2q[0].y + o.y * w2q[1].y + o.z * w2q[2].y + o.w * w2q[3].y;
#pragma unroll
        for (int off = 16; off >= 1; off >>= 1) {
            p0 += __shfl_xor(p0, off, 32);
            p1 += __shfl_xor(p1, off, 32);
        }
        if (ct == 0) ((float2*)t)[grow] = make_float2(p0 * no, p1 * no);
    }
}

// ---------------------------------------------------------------------------
// Layer-2 CSR gather fused with epilogue: out[d] = (sum t[src]) * ninv_in + b2
// ---------------------------------------------------------------------------
__global__ void final2_kernel(const float* __restrict__ t, const int* __restrict__ row_ptr,
                              const int* __restrict__ eidx, const float* __restrict__ ninv_in,
                              const float* __restrict__ b2, float* __restrict__ out, int N) {
    int i = blockIdx.x * blockDim.x + threadIdx.x;
    if (i >= N) return;
    int beg = row_ptr[i], end = row_ptr[i + 1];
    const float2* t2 = (const float2*)t;
    float ax = 0.f, ay = 0.f;
    int j = beg;
    for (; j + 4 <= end; j += 4) {
        float2 v0 = t2[eidx[j]], v1 = t2[eidx[j+1]], v2 = t2[eidx[j+2]], v3 = t2[eidx[j+3]];
        ax += v0.x + v1.x + v2.x + v3.x;
        ay += v0.y + v1.y + v2.y + v3.y;
    }
    for (; j < end; ++j) {
        float2 v = t2[eidx[j]];
        ax += v.x; ay += v.y;
    }
    float ni = ninv_in[i];
    float2 o;
    o.x = ax * ni + b2[0];
    o.y = ay * ni + b2[1];
    ((float2*)out)[i] = o;
}

// ---------------------------------------------------------------------------
extern "C" void kernel_launch(void* const* d_in, const int* in_sizes, int n_in,
                              void* d_out, int out_size, void* d_ws, size_t ws_size,
                              hipStream_t stream) {
    const float* in_feat = (const float*)d_in[0];
    const float* W1      = (const float*)d_in[1];
    const float* b1      = (const float*)d_in[2];
    const float* W2      = (const float*)d_in[3];
    const float* b2      = (const float*)d_in[4];
    const int*   src     = (const int*)d_in[5];
    const int*   dst     = (const int*)d_in[6];
    int N = in_sizes[0] / IN_F;
    int E = in_sizes[5];

    float* ws        = (float*)d_ws;
    float* B         = ws;                             // 128N floats
    float* ninv_out  = ws + (size_t)128 * N;           // N
    float* ninv_in   = ninv_out + N;                   // N
    float* t         = ninv_in + N;                    // 2N
    int*   deg_out_i = (int*)(t + (size_t)2 * N);      // N
    int*   deg_in_i  = deg_out_i + N;                  // N
    int*   excl_cur  = deg_in_i + N;                   // N
    int*   row_ptr   = excl_cur + N;                   // N+1
    int*   blockSums = row_ptr + N + 1;                // 256
    int*   eidx      = blockSums + 256;                // E

    hipMemsetAsync(deg_out_i, 0, (size_t)2 * N * sizeof(int), stream);

    deg_kernel<<<(E + 255) / 256, 256, 0, stream>>>(src, dst, deg_out_i, deg_in_i, E);
    ninv_kernel<<<(N + 255) / 256, 256, 0, stream>>>(deg_out_i, deg_in_i, ninv_out, ninv_in, N);

    int nb = (N + SCAN_CHUNK - 1) / SCAN_CHUNK;
    scan1_kernel<<<nb, 256, 0, stream>>>(deg_in_i, excl_cur, blockSums, N);
    scan2_kernel<<<1, 256, 0, stream>>>(blockSums, nb);
    scan3_kernel<<<(N + 255) / 256, 256, 0, stream>>>(excl_cur, blockSums, row_ptr, N, E);
    fill_kernel<<<(E + 255) / 256, 256, 0, stream>>>(src, dst, excl_cur, eidx, E);

    agg1_kernel<<<(N + 3) / 4, 256, 0, stream>>>(in_feat, row_ptr, eidx, ninv_out, B, N);

    mm1_kernel<<<(N + MM1_ROWS - 1) / MM1_ROWS, 256, 0, stream>>>(
        B, W1, b1, ninv_in, ninv_out, W2, t, N);

    final2_kernel<<<(N + 255) / 256, 256, 0, stream>>>(
        t, row_ptr, eidx, ninv_in, b2, (float*)d_out, N);
}

// Round 4
// 404.233 us; speedup vs baseline: 7.8294x; 1.3533x over previous
//
#include <hip/hip_runtime.h>

#define IN_F 128
#define HID  128
#define NB_SHIFT 8        // 256 nodes per dst-bucket
#define NBKT_PAD 512      // padded bucket count (real NB = ceil(N/256) = 391)
#define NCHUNK 256        // edge chunks for count/scatter passes

// ---------------------------------------------------------------------------
// deg_out histogram (src side only; 1.6M global atomics)
// ---------------------------------------------------------------------------
__global__ void degsrc_kernel(const int* __restrict__ src, int* __restrict__ deg_out, int E) {
    int i = blockIdx.x * blockDim.x + threadIdx.x;
    if (i < E) atomicAdd(&deg_out[src[i]], 1);
}

__global__ void ninvout_kernel(const int* __restrict__ dego, float* __restrict__ no, int N) {
    int i = blockIdx.x * blockDim.x + threadIdx.x;
    if (i < N) {
        int a = dego[i];
        no[i] = (a > 0) ? rsqrtf((float)a) : 0.0f;
    }
}

// ---------------------------------------------------------------------------
// Pass A: per-chunk histogram of dst buckets (LDS atomics, coalesced writes)
// ---------------------------------------------------------------------------
__global__ __launch_bounds__(256)
void countA_kernel(const int* __restrict__ dst, int* __restrict__ counts, int E, int epc) {
    __shared__ int h[NBKT_PAD];
    int tid = threadIdx.x, c = blockIdx.x;
    h[tid] = 0; h[tid + 256] = 0;
    __syncthreads();
    int lo = c * epc, hi = min(lo + epc, E);
    for (int i = lo + tid; i < hi; i += 256)
        atomicAdd(&h[dst[i] >> NB_SHIFT], 1);
    __syncthreads();
    counts[c * NBKT_PAD + tid]       = h[tid];
    counts[c * NBKT_PAD + tid + 256] = h[tid + 256];
}

// ---------------------------------------------------------------------------
// Pass B1: per-bucket exclusive scan over chunks (in place), bucket totals out
// ---------------------------------------------------------------------------
__global__ __launch_bounds__(256)
void scanB1_kernel(int* __restrict__ counts, int* __restrict__ btot) {
    __shared__ int sd[256];
    int b = blockIdx.x, tid = threadIdx.x;
    int v = counts[tid * NBKT_PAD + b];
    sd[tid] = v; __syncthreads();
    for (int off = 1; off < 256; off <<= 1) {
        int t = (tid >= off) ? sd[tid - off] : 0;
        __syncthreads();
        sd[tid] += t;
        __syncthreads();
    }
    counts[tid * NBKT_PAD + b] = sd[tid] - v;   // exclusive over chunks
    if (tid == 255) btot[b] = sd[255];
}

// ---------------------------------------------------------------------------
// Pass B2: exclusive scan of bucket totals -> bucket_base; row_ptr[N]=E
// ---------------------------------------------------------------------------
__global__ __launch_bounds__(512)
void scanB2_kernel(const int* __restrict__ btot, int* __restrict__ bbase,
                   int* __restrict__ row_ptr, int N, int E) {
    __shared__ int sd[512];
    int tid = threadIdx.x;
    int v = btot[tid];
    sd[tid] = v; __syncthreads();
    for (int off = 1; off < 512; off <<= 1) {
        int t = (tid >= off) ? sd[tid - off] : 0;
        __syncthreads();
        sd[tid] += t;
        __syncthreads();
    }
    bbase[tid] = sd[tid] - v;
    if (tid == 511) bbase[512] = sd[511];   // == E
    if (tid == 0) row_ptr[N] = E;
}

// ---------------------------------------------------------------------------
// Pass C: scatter (src,dst) pairs into bucket regions (LDS cursors; compact
// sequential writes per (chunk,bucket) sub-region)
// ---------------------------------------------------------------------------
__global__ __launch_bounds__(256)
void scatterC_kernel(const int* __restrict__ src, const int* __restrict__ dst,
                     const int* __restrict__ counts, const int* __restrict__ bbase,
                     int2* __restrict__ pairs, int E, int epc) {
    __shared__ int cur[NBKT_PAD];
    int tid = threadIdx.x, c = blockIdx.x;
    cur[tid]       = counts[c * NBKT_PAD + tid]       + bbase[tid];
    cur[tid + 256] = counts[c * NBKT_PAD + tid + 256] + bbase[tid + 256];
    __syncthreads();
    int lo = c * epc, hi = min(lo + epc, E);
    for (int i = lo + tid; i < hi; i += 256) {
        int s = src[i], d = dst[i];
        int pos = atomicAdd(&cur[d >> NB_SHIFT], 1);
        pairs[pos] = make_int2(s, d);
    }
}

// ---------------------------------------------------------------------------
// Pass D: per-bucket local counting sort -> row_ptr, ninv_in, eidx
// All atomics in LDS; global writes coalesced / bucket-local.
// ---------------------------------------------------------------------------
__global__ __launch_bounds__(256)
void buildD_kernel(const int2* __restrict__ pairs, const int* __restrict__ bbase,
                   int* __restrict__ row_ptr, float* __restrict__ ninv_in,
                   int* __restrict__ eidx, int N) {
    __shared__ int cnt[256];
    __shared__ int sd[256];
    __shared__ int cursor[256];
    int b = blockIdx.x, tid = threadIdx.x;
    int beg = bbase[b], end = bbase[b + 1];
    cnt[tid] = 0;
    __syncthreads();
    for (int i = beg + tid; i < end; i += 256)
        atomicAdd(&cnt[pairs[i].y & 255], 1);
    __syncthreads();
    int v = cnt[tid];
    sd[tid] = v; __syncthreads();
    for (int off = 1; off < 256; off <<= 1) {
        int t = (tid >= off) ? sd[tid - off] : 0;
        __syncthreads();
        sd[tid] += t;
        __syncthreads();
    }
    int excl = sd[tid] - v;
    int node = (b << NB_SHIFT) + tid;
    if (node < N) {
        row_ptr[node] = beg + excl;
        ninv_in[node] = (v > 0) ? rsqrtf((float)v) : 0.0f;
    }
    cursor[tid] = beg + excl;
    __syncthreads();
    for (int i = beg + tid; i < end; i += 256) {
        int2 p = pairs[i];
        int pos = atomicAdd(&cursor[p.y & 255], 1);
        eidx[pos] = p.x;
    }
}

// ---------------------------------------------------------------------------
// Layer-1 aggregation: one WAVE per node, lane owns a float2 of the row.
// 8-deep edge unroll -> 16 outstanding vmem per wave.
// ---------------------------------------------------------------------------
__global__ __launch_bounds__(256)
void agg1_kernel(const float* __restrict__ in_feat, const int* __restrict__ row_ptr,
                 const int* __restrict__ eidx, const float* __restrict__ ninv_out,
                 float* __restrict__ B, int N) {
    int wave = threadIdx.x >> 6;
    int lane = threadIdx.x & 63;
    int d = blockIdx.x * 4 + wave;
    if (d >= N) return;
    int beg = row_ptr[d], end = row_ptr[d + 1];
    const float2* f2 = (const float2*)in_feat;
    float2 acc = make_float2(0.f, 0.f);
    int j = beg;
    for (; j + 8 <= end; j += 8) {
        int s0 = eidx[j+0], s1 = eidx[j+1], s2 = eidx[j+2], s3 = eidx[j+3];
        int s4 = eidx[j+4], s5 = eidx[j+5], s6 = eidx[j+6], s7 = eidx[j+7];
        float n0 = ninv_out[s0], n1 = ninv_out[s1], n2 = ninv_out[s2], n3 = ninv_out[s3];
        float n4 = ninv_out[s4], n5 = ninv_out[s5], n6 = ninv_out[s6], n7 = ninv_out[s7];
        float2 v0 = f2[(long)s0*64+lane], v1 = f2[(long)s1*64+lane];
        float2 v2 = f2[(long)s2*64+lane], v3 = f2[(long)s3*64+lane];
        float2 v4 = f2[(long)s4*64+lane], v5 = f2[(long)s5*64+lane];
        float2 v6 = f2[(long)s6*64+lane], v7 = f2[(long)s7*64+lane];
        acc.x += v0.x*n0 + v1.x*n1 + v2.x*n2 + v3.x*n3 + v4.x*n4 + v5.x*n5 + v6.x*n6 + v7.x*n7;
        acc.y += v0.y*n0 + v1.y*n1 + v2.y*n2 + v3.y*n3 + v4.y*n4 + v5.y*n5 + v6.y*n6 + v7.y*n7;
    }
    for (; j + 2 <= end; j += 2) {
        int s0 = eidx[j], s1 = eidx[j+1];
        float n0 = ninv_out[s0], n1 = ninv_out[s1];
        float2 v0 = f2[(long)s0*64+lane], v1 = f2[(long)s1*64+lane];
        acc.x += v0.x*n0 + v1.x*n1;
        acc.y += v0.y*n0 + v1.y*n1;
    }
    if (j < end) {
        int s = eidx[j];
        float n = ninv_out[s];
        float2 v = f2[(long)s*64+lane];
        acc.x += v.x*n; acc.y += v.y*n;
    }
    ((float2*)B)[(long)d*64 + lane] = acc;
}

// ---------------------------------------------------------------------------
// Fused mm1+mm2: t[row] = ninv_out[row] * (relu(B[row]@W1 * ninv_in + b1) @ W2)
// ---------------------------------------------------------------------------
#define MM1_ROWS 32
__global__ __launch_bounds__(256, 2)
void mm1_kernel(const float* __restrict__ B, const float* __restrict__ W1,
                const float* __restrict__ b1, const float* __restrict__ ninv_in,
                const float* __restrict__ ninv_out, const float* __restrict__ W2,
                float* __restrict__ t, int N) {
    __shared__ float ws[IN_F * HID];          // [k][c], 64KB
    __shared__ float xs[MM1_ROWS * IN_F];     // 16KB
    int tid = threadIdx.x;
    int row0 = blockIdx.x * MM1_ROWS;

    float4* ws4 = (float4*)ws;
    const float4* w14 = (const float4*)W1;
#pragma unroll
    for (int j = 0; j < 16; ++j) ws4[j * 256 + tid] = w14[j * 256 + tid];

    float4* xs4 = (float4*)xs;
    const float4* B4 = (const float4*)B;
#pragma unroll
    for (int j = 0; j < 4; ++j) {
        int idx = j * 256 + tid;
        int r = idx >> 5, k4 = idx & 31;
        int grow = row0 + r;
        xs4[idx] = (grow < N) ? B4[(long)grow * 32 + k4] : make_float4(0.f, 0.f, 0.f, 0.f);
    }

    int ct = tid & 31;
    int rt = tid >> 5;
    const float2* W2v = (const float2*)W2;
    float2 w2q[4];
#pragma unroll
    for (int q = 0; q < 4; ++q) w2q[q] = W2v[4 * ct + q];
    float4 b1v = ((const float4*)b1)[ct];
    __syncthreads();

    float4 acc[4];
#pragma unroll
    for (int i = 0; i < 4; ++i) acc[i] = make_float4(0.f, 0.f, 0.f, 0.f);

#pragma unroll 8
    for (int k4 = 0; k4 < 32; ++k4) {
        float4 wa = ws4[(4 * k4 + 0) * 32 + ct];
        float4 wb = ws4[(4 * k4 + 1) * 32 + ct];
        float4 wc = ws4[(4 * k4 + 2) * 32 + ct];
        float4 wd = ws4[(4 * k4 + 3) * 32 + ct];
#pragma unroll
        for (int i = 0; i < 4; ++i) {
            float4 x = xs4[(4 * rt + i) * 32 + k4];
            acc[i].x += x.x * wa.x + x.y * wb.x + x.z * wc.x + x.w * wd.x;
            acc[i].y += x.x * wa.y + x.y * wb.y + x.z * wc.y + x.w * wd.y;
            acc[i].z += x.x * wa.z + x.y * wb.z + x.z * wc.z + x.w * wd.z;
            acc[i].w += x.x * wa.w + x.y * wb.w + x.z * wc.w + x.w * wd.w;
        }
    }

#pragma unroll
    for (int i = 0; i < 4; ++i) {
        int grow = row0 + 4 * rt + i;
        if (grow >= N) continue;
        float ni = ninv_in[grow];
        float no = ninv_out[grow];
        float4 o;
        o.x = fmaxf(acc[i].x * ni + b1v.x, 0.f);
        o.y = fmaxf(acc[i].y * ni + b1v.y, 0.f);
        o.z = fmaxf(acc[i].z * ni + b1v.z, 0.f);
        o.w = fmaxf(acc[i].w * ni + b1v.w, 0.f);
        float p0 = o.x * w2q[0].x + o.y * w2q[1].x + o.z * w2q[2].x + o.w * w2q[3].x;
        float p1 = o.x * w2q[0].y + o.y * w2q[1].y + o.z * w2q[2].y + o.w * w2q[3].y;
#pragma unroll
        for (int off = 16; off >= 1; off >>= 1) {
            p0 += __shfl_xor(p0, off, 32);
            p1 += __shfl_xor(p1, off, 32);
        }
        if (ct == 0) ((float2*)t)[grow] = make_float2(p0 * no, p1 * no);
    }
}

// ---------------------------------------------------------------------------
// Layer-2 CSR gather fused with epilogue
// ---------------------------------------------------------------------------
__global__ void final2_kernel(const float* __restrict__ t, const int* __restrict__ row_ptr,
                              const int* __restrict__ eidx, const float* __restrict__ ninv_in,
                              const float* __restrict__ b2, float* __restrict__ out, int N) {
    int i = blockIdx.x * blockDim.x + threadIdx.x;
    if (i >= N) return;
    int beg = row_ptr[i], end = row_ptr[i + 1];
    const float2* t2 = (const float2*)t;
    float ax = 0.f, ay = 0.f;
    int j = beg;
    for (; j + 4 <= end; j += 4) {
        float2 v0 = t2[eidx[j]], v1 = t2[eidx[j+1]], v2 = t2[eidx[j+2]], v3 = t2[eidx[j+3]];
        ax += v0.x + v1.x + v2.x + v3.x;
        ay += v0.y + v1.y + v2.y + v3.y;
    }
    for (; j < end; ++j) {
        float2 v = t2[eidx[j]];
        ax += v.x; ay += v.y;
    }
    float ni = ninv_in[i];
    float2 o;
    o.x = ax * ni + b2[0];
    o.y = ay * ni + b2[1];
    ((float2*)out)[i] = o;
}

// ---------------------------------------------------------------------------
extern "C" void kernel_launch(void* const* d_in, const int* in_sizes, int n_in,
                              void* d_out, int out_size, void* d_ws, size_t ws_size,
                              hipStream_t stream) {
    const float* in_feat = (const float*)d_in[0];
    const float* W1      = (const float*)d_in[1];
    const float* b1      = (const float*)d_in[2];
    const float* W2      = (const float*)d_in[3];
    const float* b2      = (const float*)d_in[4];
    const int*   src     = (const int*)d_in[5];
    const int*   dst     = (const int*)d_in[6];
    int N = in_sizes[0] / IN_F;
    int E = in_sizes[5];
    int NB = (N + 255) >> 8;

    // workspace layout
    float* ws       = (float*)d_ws;
    float* B        = ws;                              // 128N floats (pairs alias)
    float* ninv_out = ws + (size_t)128 * N;            // N
    float* ninv_in  = ninv_out + N;                    // N
    float* t        = ninv_in + N;                     // 2N
    int*   deg_out  = (int*)(t + (size_t)2 * N);       // N
    int*   row_ptr  = deg_out + N;                     // N+1
    int*   eidx     = row_ptr + N + 1;                 // E
    int*   counts   = eidx + E;                        // NCHUNK*NBKT_PAD
    int*   btot     = counts + NCHUNK * NBKT_PAD;      // 512
    int*   bbase    = btot + 512;                      // 513
    int2*  pairs    = (int2*)B;                        // 2E ints, consumed before agg1

    int epc = (E + NCHUNK - 1) / NCHUNK;

    hipMemsetAsync(deg_out, 0, (size_t)N * sizeof(int), stream);

    degsrc_kernel<<<(E + 255) / 256, 256, 0, stream>>>(src, deg_out, E);
    countA_kernel<<<NCHUNK, 256, 0, stream>>>(dst, counts, E, epc);
    scanB1_kernel<<<NBKT_PAD, 256, 0, stream>>>(counts, btot);
    scanB2_kernel<<<1, 512, 0, stream>>>(btot, bbase, row_ptr, N, E);
    scatterC_kernel<<<NCHUNK, 256, 0, stream>>>(src, dst, counts, bbase, pairs, E, epc);
    buildD_kernel<<<NB, 256, 0, stream>>>(pairs, bbase, row_ptr, ninv_in, eidx, N);
    ninvout_kernel<<<(N + 255) / 256, 256, 0, stream>>>(deg_out, ninv_out, N);

    agg1_kernel<<<(N + 3) / 4, 256, 0, stream>>>(in_feat, row_ptr, eidx, ninv_out, B, N);

    mm1_kernel<<<(N + MM1_ROWS - 1) / MM1_ROWS, 256, 0, stream>>>(
        B, W1, b1, ninv_in, ninv_out, W2, t, N);

    final2_kernel<<<(N + 255) / 256, 256, 0, stream>>>(
        t, row_ptr, eidx, ninv_in, b2, (float*)d_out, N);
}

// Round 5
// 324.643 us; speedup vs baseline: 9.7488x; 1.2452x over previous
//
#include <hip/hip_runtime.h>

#define IN_F 128
#define HID  128
#define NB_SHIFT 8        // 256 nodes per bucket
#define NBKT 512          // padded bucket count (real NB = ceil(N/256) = 391)
#define NCHUNK 256        // edge chunks for count/scatter passes

// ---- bf16 helpers (RNE pack, shift-unpack) --------------------------------
__device__ __forceinline__ unsigned int bfround(float x) {
    unsigned int u = __float_as_uint(x);
    return (u + 0x7fffu + ((u >> 16) & 1u)) >> 16;
}
__device__ __forceinline__ unsigned int pack2(float a, float b) {
    return bfround(a) | (bfround(b) << 16);
}
__device__ __forceinline__ float lo_f(unsigned int u) { return __uint_as_float(u << 16); }
__device__ __forceinline__ float hi_f(unsigned int u) { return __uint_as_float(u & 0xffff0000u); }

// ---------------------------------------------------------------------------
// Pass A: per-chunk histograms of BOTH src and dst buckets (LDS atomics)
// ---------------------------------------------------------------------------
__global__ __launch_bounds__(256)
void countAB_kernel(const int* __restrict__ src, const int* __restrict__ dst,
                    int* __restrict__ cd, int* __restrict__ cs, int E, int epc) {
    __shared__ int hd[NBKT], hs[NBKT];
    int tid = threadIdx.x, c = blockIdx.x;
    hd[tid] = 0; hd[tid + 256] = 0; hs[tid] = 0; hs[tid + 256] = 0;
    __syncthreads();
    int lo = c * epc, hi = min(lo + epc, E);
    for (int i = lo + tid; i < hi; i += 256) {
        atomicAdd(&hd[dst[i] >> NB_SHIFT], 1);
        atomicAdd(&hs[src[i] >> NB_SHIFT], 1);
    }
    __syncthreads();
    cd[c * NBKT + tid] = hd[tid]; cd[c * NBKT + tid + 256] = hd[tid + 256];
    cs[c * NBKT + tid] = hs[tid]; cs[c * NBKT + tid + 256] = hs[tid + 256];
}

// ---------------------------------------------------------------------------
// Pass B1: per-bucket exclusive scan over chunks (in place), bucket totals out
// grid = 2*NBKT: first half dst, second half src
// ---------------------------------------------------------------------------
__global__ __launch_bounds__(256)
void scanB1_kernel(int* __restrict__ cd, int* __restrict__ cs,
                   int* __restrict__ btd, int* __restrict__ bts) {
    __shared__ int sd[256];
    int b = blockIdx.x, tid = threadIdx.x;
    int* arr = (b < NBKT) ? cd : cs;
    int* bt  = (b < NBKT) ? btd : bts;
    int col = b & (NBKT - 1);
    int v = arr[tid * NBKT + col];
    sd[tid] = v; __syncthreads();
    for (int off = 1; off < 256; off <<= 1) {
        int t = (tid >= off) ? sd[tid - off] : 0;
        __syncthreads();
        sd[tid] += t;
        __syncthreads();
    }
    arr[tid * NBKT + col] = sd[tid] - v;
    if (tid == 255) bt[col] = sd[255];
}

// ---------------------------------------------------------------------------
// Pass B2: exclusive scans of bucket totals (grid=2: dst, src)
// ---------------------------------------------------------------------------
__global__ __launch_bounds__(512)
void scanB2_kernel(const int* __restrict__ btd, const int* __restrict__ bts,
                   int* __restrict__ bbd, int* __restrict__ bbs,
                   int* __restrict__ row_ptr, int N, int E) {
    __shared__ int sd[512];
    int tid = threadIdx.x;
    const int* bt = blockIdx.x ? bts : btd;
    int* bb = blockIdx.x ? bbs : bbd;
    int v = bt[tid];
    sd[tid] = v; __syncthreads();
    for (int off = 1; off < 512; off <<= 1) {
        int t = (tid >= off) ? sd[tid - off] : 0;
        __syncthreads();
        sd[tid] += t;
        __syncthreads();
    }
    bb[tid] = sd[tid] - v;
    if (tid == 511) bb[512] = sd[511];  // == E
    if (blockIdx.x == 0 && tid == 0) row_ptr[N] = E;
}

// ---------------------------------------------------------------------------
// Pass C: scatter packed dst-pairs (src | dstLow<<17, one int) into dst-bucket
// regions AND src low-bytes into src-bucket regions. LDS cursors, no global
// atomics.
// ---------------------------------------------------------------------------
__global__ __launch_bounds__(256)
void scatterAB_kernel(const int* __restrict__ src, const int* __restrict__ dst,
                      const int* __restrict__ cd, const int* __restrict__ cs,
                      const int* __restrict__ bbd, const int* __restrict__ bbs,
                      int* __restrict__ pairs, unsigned char* __restrict__ sbytes,
                      int E, int epc) {
    __shared__ int curd[NBKT], curs[NBKT];
    int tid = threadIdx.x, c = blockIdx.x;
    curd[tid]       = cd[c * NBKT + tid]       + bbd[tid];
    curd[tid + 256] = cd[c * NBKT + tid + 256] + bbd[tid + 256];
    curs[tid]       = cs[c * NBKT + tid]       + bbs[tid];
    curs[tid + 256] = cs[c * NBKT + tid + 256] + bbs[tid + 256];
    __syncthreads();
    int lo = c * epc, hi = min(lo + epc, E);
    for (int i = lo + tid; i < hi; i += 256) {
        int s = src[i], d = dst[i];
        int pd = atomicAdd(&curd[d >> NB_SHIFT], 1);
        pairs[pd] = s | ((d & 255) << 17);          // src < 2^17
        int ps = atomicAdd(&curs[s >> NB_SHIFT], 1);
        sbytes[ps] = (unsigned char)(s & 255);
    }
}

// ---------------------------------------------------------------------------
// Pass D (dst): per-bucket counting sort -> row_ptr, ninv_in, eidx
// ---------------------------------------------------------------------------
__global__ __launch_bounds__(256)
void buildD_kernel(const int* __restrict__ pairs, const int* __restrict__ bbd,
                   int* __restrict__ row_ptr, float* __restrict__ ninv_in,
                   int* __restrict__ eidx, int N) {
    __shared__ int cnt[256], sd[256], cursor[256];
    int b = blockIdx.x, tid = threadIdx.x;
    int beg = bbd[b], end = bbd[b + 1];
    cnt[tid] = 0;
    __syncthreads();
    for (int i = beg + tid; i < end; i += 256)
        atomicAdd(&cnt[(pairs[i] >> 17) & 255], 1);
    __syncthreads();
    int v = cnt[tid];
    sd[tid] = v; __syncthreads();
    for (int off = 1; off < 256; off <<= 1) {
        int t = (tid >= off) ? sd[tid - off] : 0;
        __syncthreads();
        sd[tid] += t;
        __syncthreads();
    }
    int excl = sd[tid] - v;
    int node = (b << NB_SHIFT) + tid;
    if (node < N) {
        row_ptr[node] = beg + excl;
        ninv_in[node] = (v > 0) ? rsqrtf((float)v) : 0.0f;
    }
    cursor[tid] = beg + excl;
    __syncthreads();
    for (int i = beg + tid; i < end; i += 256) {
        int p = pairs[i];
        int pos = atomicAdd(&cursor[(p >> 17) & 255], 1);
        eidx[pos] = p & 0x1FFFF;
    }
}

// ---------------------------------------------------------------------------
// Pass D (src): per-bucket byte histogram -> ninv_out (deg_out never stored)
// ---------------------------------------------------------------------------
__global__ __launch_bounds__(256)
void buildDsrc_kernel(const unsigned char* __restrict__ sbytes, const int* __restrict__ bbs,
                      float* __restrict__ ninv_out, int N) {
    __shared__ int cnt[256];
    int b = blockIdx.x, tid = threadIdx.x;
    int beg = bbs[b], end = bbs[b + 1];
    cnt[tid] = 0;
    __syncthreads();
    for (int i = beg + tid; i < end; i += 256)
        atomicAdd(&cnt[sbytes[i]], 1);
    __syncthreads();
    int node = (b << NB_SHIFT) + tid;
    if (node < N) {
        int v = cnt[tid];
        ninv_out[node] = (v > 0) ? rsqrtf((float)v) : 0.0f;
    }
}

// ---------------------------------------------------------------------------
// conv: xb = bf16(in_feat * ninv_out)  — 25.6 MB gather table, prescaled
// ---------------------------------------------------------------------------
__global__ __launch_bounds__(256)
void conv_kernel(const float* __restrict__ in_feat, const float* __restrict__ ninv_out,
                 unsigned int* __restrict__ xb, int N) {
    int gid = blockIdx.x * 256 + threadIdx.x;   // [0, N*32)
    if (gid >= N * 32) return;
    int r = gid >> 5, q = gid & 31;
    float no = ninv_out[r];
    float4 v = ((const float4*)in_feat)[(long)r * 32 + q];
    uint2 o;
    o.x = pack2(v.x * no, v.y * no);
    o.y = pack2(v.z * no, v.w * no);
    ((uint2*)xb)[(long)r * 32 + q] = o;
}

// ---------------------------------------------------------------------------
// Layer-1 aggregation: one WAVE per node, lane owns one uint (2 bf16).
// 8-deep edge unroll; pure adds (prescaled); output row packed bf16.
// ---------------------------------------------------------------------------
__global__ __launch_bounds__(256)
void agg1_kernel(const unsigned int* __restrict__ xb, const int* __restrict__ row_ptr,
                 const int* __restrict__ eidx, unsigned int* __restrict__ Bb, int N) {
    int wave = threadIdx.x >> 6;
    int lane = threadIdx.x & 63;
    int d = blockIdx.x * 4 + wave;
    if (d >= N) return;
    int beg = row_ptr[d], end = row_ptr[d + 1];
    float ax = 0.f, ay = 0.f;
    int j = beg;
    for (; j + 8 <= end; j += 8) {
        int s0 = eidx[j+0], s1 = eidx[j+1], s2 = eidx[j+2], s3 = eidx[j+3];
        int s4 = eidx[j+4], s5 = eidx[j+5], s6 = eidx[j+6], s7 = eidx[j+7];
        unsigned int u0 = xb[(long)s0*64+lane], u1 = xb[(long)s1*64+lane];
        unsigned int u2 = xb[(long)s2*64+lane], u3 = xb[(long)s3*64+lane];
        unsigned int u4 = xb[(long)s4*64+lane], u5 = xb[(long)s5*64+lane];
        unsigned int u6 = xb[(long)s6*64+lane], u7 = xb[(long)s7*64+lane];
        ax += lo_f(u0) + lo_f(u1) + lo_f(u2) + lo_f(u3)
            + lo_f(u4) + lo_f(u5) + lo_f(u6) + lo_f(u7);
        ay += hi_f(u0) + hi_f(u1) + hi_f(u2) + hi_f(u3)
            + hi_f(u4) + hi_f(u5) + hi_f(u6) + hi_f(u7);
    }
    for (; j + 2 <= end; j += 2) {
        unsigned int u0 = xb[(long)eidx[j]*64+lane], u1 = xb[(long)eidx[j+1]*64+lane];
        ax += lo_f(u0) + lo_f(u1);
        ay += hi_f(u0) + hi_f(u1);
    }
    if (j < end) {
        unsigned int u = xb[(long)eidx[j]*64+lane];
        ax += lo_f(u); ay += hi_f(u);
    }
    Bb[(long)d * 64 + lane] = pack2(ax, ay);
}

// ---------------------------------------------------------------------------
// Fused mm1+mm2: t[row] = ninv_out[row] * (relu(B[row]@W1 * ninv_in + b1) @ W2)
// B read as packed bf16, unpacked to f32 LDS tile; compute in f32 VALU.
// ---------------------------------------------------------------------------
#define MM1_ROWS 32
__global__ __launch_bounds__(256, 2)
void mm1_kernel(const unsigned int* __restrict__ Bb, const float* __restrict__ W1,
                const float* __restrict__ b1, const float* __restrict__ ninv_in,
                const float* __restrict__ ninv_out, const float* __restrict__ W2,
                float* __restrict__ t, int N) {
    __shared__ float ws[IN_F * HID];          // [k][c], 64KB
    __shared__ float xs[MM1_ROWS * IN_F];     // 16KB
    int tid = threadIdx.x;
    int row0 = blockIdx.x * MM1_ROWS;

    float4* ws4 = (float4*)ws;
    const float4* w14 = (const float4*)W1;
#pragma unroll
    for (int j = 0; j < 16; ++j) ws4[j * 256 + tid] = w14[j * 256 + tid];

    // stage x tile: 32 rows x 64 uints (2 bf16 each) -> f32 LDS
    float2* xs2 = (float2*)xs;
#pragma unroll
    for (int j = 0; j < 8; ++j) {
        int idx = j * 256 + tid;          // uint index in tile [0, 2048)
        int r = idx >> 6, p = idx & 63;
        int grow = row0 + r;
        unsigned int u = (grow < N) ? Bb[(long)grow * 64 + p] : 0u;
        xs2[r * 64 + p] = make_float2(lo_f(u), hi_f(u));
    }

    int ct = tid & 31;
    int rt = tid >> 5;
    const float2* W2v = (const float2*)W2;
    float2 w2q[4];
#pragma unroll
    for (int q = 0; q < 4; ++q) w2q[q] = W2v[4 * ct + q];
    float4 b1v = ((const float4*)b1)[ct];
    __syncthreads();

    float4 acc[4];
#pragma unroll
    for (int i = 0; i < 4; ++i) acc[i] = make_float4(0.f, 0.f, 0.f, 0.f);

    float4* xs4 = (float4*)xs;
#pragma unroll 8
    for (int k4 = 0; k4 < 32; ++k4) {
        float4 wa = ws4[(4 * k4 + 0) * 32 + ct];
        float4 wb = ws4[(4 * k4 + 1) * 32 + ct];
        float4 wc = ws4[(4 * k4 + 2) * 32 + ct];
        float4 wd = ws4[(4 * k4 + 3) * 32 + ct];
#pragma unroll
        for (int i = 0; i < 4; ++i) {
            float4 x = xs4[(4 * rt + i) * 32 + k4];
            acc[i].x += x.x * wa.x + x.y * wb.x + x.z * wc.x + x.w * wd.x;
            acc[i].y += x.x * wa.y + x.y * wb.y + x.z * wc.y + x.w * wd.y;
            acc[i].z += x.x * wa.z + x.y * wb.z + x.z * wc.z + x.w * wd.z;
            acc[i].w += x.x * wa.w + x.y * wb.w + x.z * wc.w + x.w * wd.w;
        }
    }

#pragma unroll
    for (int i = 0; i < 4; ++i) {
        int grow = row0 + 4 * rt + i;
        if (grow >= N) continue;
        float ni = ninv_in[grow];
        float no = ninv_out[grow];
        float4 o;
        o.x = fmaxf(acc[i].x * ni + b1v.x, 0.f);
        o.y = fmaxf(acc[i].y * ni + b1v.y, 0.f);
        o.z = fmaxf(acc[i].z * ni + b1v.z, 0.f);
        o.w = fmaxf(acc[i].w * ni + b1v.w, 0.f);
        float p0 = o.x * w2q[0].x + o.y * w2q[1].x + o.z * w2q[2].x + o.w * w2q[3].x;
        float p1 = o.x * w2q[0].y + o.y * w2q[1].y + o.z * w2q[2].y + o.w * w2q[3].y;
#pragma unroll
        for (int off = 16; off >= 1; off >>= 1) {
            p0 += __shfl_xor(p0, off, 32);
            p1 += __shfl_xor(p1, off, 32);
        }
        if (ct == 0) ((float2*)t)[grow] = make_float2(p0 * no, p1 * no);
    }
}

// ---------------------------------------------------------------------------
// Layer-2 CSR gather fused with epilogue
// ---------------------------------------------------------------------------
__global__ void final2_kernel(const float* __restrict__ t, const int* __restrict__ row_ptr,
                              const int* __restrict__ eidx, const float* __restrict__ ninv_in,
                              const float* __restrict__ b2, float* __restrict__ out, int N) {
    int i = blockIdx.x * blockDim.x + threadIdx.x;
    if (i >= N) return;
    int beg = row_ptr[i], end = row_ptr[i + 1];
    const float2* t2 = (const float2*)t;
    float ax = 0.f, ay = 0.f;
    int j = beg;
    for (; j + 4 <= end; j += 4) {
        float2 v0 = t2[eidx[j]], v1 = t2[eidx[j+1]], v2 = t2[eidx[j+2]], v3 = t2[eidx[j+3]];
        ax += v0.x + v1.x + v2.x + v3.x;
        ay += v0.y + v1.y + v2.y + v3.y;
    }
    for (; j < end; ++j) {
        float2 v = t2[eidx[j]];
        ax += v.x; ay += v.y;
    }
    float ni = ninv_in[i];
    float2 o;
    o.x = ax * ni + b2[0];
    o.y = ay * ni + b2[1];
    ((float2*)out)[i] = o;
}

// ---------------------------------------------------------------------------
extern "C" void kernel_launch(void* const* d_in, const int* in_sizes, int n_in,
                              void* d_out, int out_size, void* d_ws, size_t ws_size,
                              hipStream_t stream) {
    const float* in_feat = (const float*)d_in[0];
    const float* W1      = (const float*)d_in[1];
    const float* b1      = (const float*)d_in[2];
    const float* W2      = (const float*)d_in[3];
    const float* b2      = (const float*)d_in[4];
    const int*   src     = (const int*)d_in[5];
    const int*   dst     = (const int*)d_in[6];
    int N = in_sizes[0] / IN_F;
    int E = in_sizes[5];
    int NB = (N + 255) >> 8;

    // workspace layout (bytes):
    //  Bb   : N*64 uints (25.6MB)  -- bf16 h1/h2 rows; pairs+sbytes alias here
    //  xb   : N*64 uints (25.6MB)  -- bf16 prescaled in_feat
    //  then f32/int arrays
    unsigned int* Bb  = (unsigned int*)d_ws;
    int*   pairs      = (int*)Bb;                            // E ints (consumed pre-agg1)
    unsigned char* sbytes = (unsigned char*)(Bb + E);        // E bytes (consumed pre-agg1)
    unsigned int* xb  = Bb + (size_t)64 * N;
    float* ninv_out   = (float*)(xb + (size_t)64 * N);       // N
    float* ninv_in    = ninv_out + N;                        // N
    float* t          = ninv_in + N;                         // 2N
    int*   row_ptr    = (int*)(t + (size_t)2 * N);           // N+1
    int*   eidx       = row_ptr + N + 1;                     // E
    int*   cd         = eidx + E;                            // NCHUNK*NBKT
    int*   cs         = cd + NCHUNK * NBKT;                  // NCHUNK*NBKT
    int*   btd        = cs + NCHUNK * NBKT;                  // 512
    int*   bts        = btd + NBKT;                          // 512
    int*   bbd        = bts + NBKT;                          // 513
    int*   bbs        = bbd + NBKT + 1;                      // 513

    int epc = (E + NCHUNK - 1) / NCHUNK;

    countAB_kernel<<<NCHUNK, 256, 0, stream>>>(src, dst, cd, cs, E, epc);
    scanB1_kernel<<<2 * NBKT, 256, 0, stream>>>(cd, cs, btd, bts);
    scanB2_kernel<<<2, 512, 0, stream>>>(btd, bts, bbd, bbs, row_ptr, N, E);
    scatterAB_kernel<<<NCHUNK, 256, 0, stream>>>(src, dst, cd, cs, bbd, bbs,
                                                 pairs, sbytes, E, epc);
    buildD_kernel<<<NB, 256, 0, stream>>>(pairs, bbd, row_ptr, ninv_in, eidx, N);
    buildDsrc_kernel<<<NB, 256, 0, stream>>>(sbytes, bbs, ninv_out, N);

    conv_kernel<<<(N * 32 + 255) / 256, 256, 0, stream>>>(in_feat, ninv_out, xb, N);

    agg1_kernel<<<(N + 3) / 4, 256, 0, stream>>>(xb, row_ptr, eidx, Bb, N);

    mm1_kernel<<<(N + MM1_ROWS - 1) / MM1_ROWS, 256, 0, stream>>>(
        Bb, W1, b1, ninv_in, ninv_out, W2, t, N);

    final2_kernel<<<(N + 255) / 256, 256, 0, stream>>>(
        t, row_ptr, eidx, ninv_in, b2, (float*)d_out, N);
}

// Round 6
// 258.566 us; speedup vs baseline: 12.2402x; 1.2556x over previous
//
#include <hip/hip_runtime.h>

#define IN_F 128
#define HID  128
#define NB_SHIFT 8        // 256 nodes per bucket
#define NBKT 512          // padded bucket count (real NB = ceil(N/256) = 391)
#define NCHUNK 256        // edge chunks for count/scatter passes

typedef __bf16 bf16x8 __attribute__((ext_vector_type(8)));
typedef float f32x4 __attribute__((ext_vector_type(4)));
union U8 { uint4 u; bf16x8 v; };

// ---- bf16 helpers (RNE pack, shift-unpack) --------------------------------
__device__ __forceinline__ unsigned int bfround(float x) {
    unsigned int u = __float_as_uint(x);
    return (u + 0x7fffu + ((u >> 16) & 1u)) >> 16;
}
__device__ __forceinline__ unsigned int pack2(float a, float b) {
    return bfround(a) | (bfround(b) << 16);
}
__device__ __forceinline__ float lo_f(unsigned int u) { return __uint_as_float(u << 16); }
__device__ __forceinline__ float hi_f(unsigned int u) { return __uint_as_float(u & 0xffff0000u); }

// ---------------------------------------------------------------------------
// Pass A: per-chunk histograms of BOTH src and dst buckets (LDS atomics)
// ---------------------------------------------------------------------------
__global__ __launch_bounds__(256)
void countAB_kernel(const int* __restrict__ src, const int* __restrict__ dst,
                    int* __restrict__ cd, int* __restrict__ cs, int E, int epc) {
    __shared__ int hd[NBKT], hs[NBKT];
    int tid = threadIdx.x, c = blockIdx.x;
    hd[tid] = 0; hd[tid + 256] = 0; hs[tid] = 0; hs[tid + 256] = 0;
    __syncthreads();
    int lo = c * epc, hi = min(lo + epc, E);
    for (int i = lo + tid; i < hi; i += 256) {
        atomicAdd(&hd[dst[i] >> NB_SHIFT], 1);
        atomicAdd(&hs[src[i] >> NB_SHIFT], 1);
    }
    __syncthreads();
    cd[c * NBKT + tid] = hd[tid]; cd[c * NBKT + tid + 256] = hd[tid + 256];
    cs[c * NBKT + tid] = hs[tid]; cs[c * NBKT + tid + 256] = hs[tid + 256];
}

// ---------------------------------------------------------------------------
// Pass B1: per-bucket exclusive scan over chunks (in place), bucket totals out
// ---------------------------------------------------------------------------
__global__ __launch_bounds__(256)
void scanB1_kernel(int* __restrict__ cd, int* __restrict__ cs,
                   int* __restrict__ btd, int* __restrict__ bts) {
    __shared__ int sd[256];
    int b = blockIdx.x, tid = threadIdx.x;
    int* arr = (b < NBKT) ? cd : cs;
    int* bt  = (b < NBKT) ? btd : bts;
    int col = b & (NBKT - 1);
    int v = arr[tid * NBKT + col];
    sd[tid] = v; __syncthreads();
    for (int off = 1; off < 256; off <<= 1) {
        int t = (tid >= off) ? sd[tid - off] : 0;
        __syncthreads();
        sd[tid] += t;
        __syncthreads();
    }
    arr[tid * NBKT + col] = sd[tid] - v;
    if (tid == 255) bt[col] = sd[255];
}

// ---------------------------------------------------------------------------
// Pass B2: exclusive scans of bucket totals (grid=2: dst, src)
// ---------------------------------------------------------------------------
__global__ __launch_bounds__(512)
void scanB2_kernel(const int* __restrict__ btd, const int* __restrict__ bts,
                   int* __restrict__ bbd, int* __restrict__ bbs,
                   int* __restrict__ row_ptr, int N, int E) {
    __shared__ int sd[512];
    int tid = threadIdx.x;
    const int* bt = blockIdx.x ? bts : btd;
    int* bb = blockIdx.x ? bbs : bbd;
    int v = bt[tid];
    sd[tid] = v; __syncthreads();
    for (int off = 1; off < 512; off <<= 1) {
        int t = (tid >= off) ? sd[tid - off] : 0;
        __syncthreads();
        sd[tid] += t;
        __syncthreads();
    }
    bb[tid] = sd[tid] - v;
    if (tid == 511) bb[512] = sd[511];  // == E
    if (blockIdx.x == 0 && tid == 0) row_ptr[N] = E;
}

// ---------------------------------------------------------------------------
// Pass C: scatter packed dst-pairs + src low-bytes (LDS cursors)
// ---------------------------------------------------------------------------
__global__ __launch_bounds__(256)
void scatterAB_kernel(const int* __restrict__ src, const int* __restrict__ dst,
                      const int* __restrict__ cd, const int* __restrict__ cs,
                      const int* __restrict__ bbd, const int* __restrict__ bbs,
                      int* __restrict__ pairs, unsigned char* __restrict__ sbytes,
                      int E, int epc) {
    __shared__ int curd[NBKT], curs[NBKT];
    int tid = threadIdx.x, c = blockIdx.x;
    curd[tid]       = cd[c * NBKT + tid]       + bbd[tid];
    curd[tid + 256] = cd[c * NBKT + tid + 256] + bbd[tid + 256];
    curs[tid]       = cs[c * NBKT + tid]       + bbs[tid];
    curs[tid + 256] = cs[c * NBKT + tid + 256] + bbs[tid + 256];
    __syncthreads();
    int lo = c * epc, hi = min(lo + epc, E);
    for (int i = lo + tid; i < hi; i += 256) {
        int s = src[i], d = dst[i];
        int pd = atomicAdd(&curd[d >> NB_SHIFT], 1);
        pairs[pd] = s | ((d & 255) << 17);          // src < 2^17
        int ps = atomicAdd(&curs[s >> NB_SHIFT], 1);
        sbytes[ps] = (unsigned char)(s & 255);
    }
}

// ---------------------------------------------------------------------------
// Pass D (dst): per-bucket counting sort -> row_ptr, ninv_in, eidx
// ---------------------------------------------------------------------------
__global__ __launch_bounds__(256)
void buildD_kernel(const int* __restrict__ pairs, const int* __restrict__ bbd,
                   int* __restrict__ row_ptr, float* __restrict__ ninv_in,
                   int* __restrict__ eidx, int N) {
    __shared__ int cnt[256], sd[256], cursor[256];
    int b = blockIdx.x, tid = threadIdx.x;
    int beg = bbd[b], end = bbd[b + 1];
    cnt[tid] = 0;
    __syncthreads();
    for (int i = beg + tid; i < end; i += 256)
        atomicAdd(&cnt[(pairs[i] >> 17) & 255], 1);
    __syncthreads();
    int v = cnt[tid];
    sd[tid] = v; __syncthreads();
    for (int off = 1; off < 256; off <<= 1) {
        int t = (tid >= off) ? sd[tid - off] : 0;
        __syncthreads();
        sd[tid] += t;
        __syncthreads();
    }
    int excl = sd[tid] - v;
    int node = (b << NB_SHIFT) + tid;
    if (node < N) {
        row_ptr[node] = beg + excl;
        ninv_in[node] = (v > 0) ? rsqrtf((float)v) : 0.0f;
    }
    cursor[tid] = beg + excl;
    __syncthreads();
    for (int i = beg + tid; i < end; i += 256) {
        int p = pairs[i];
        int pos = atomicAdd(&cursor[(p >> 17) & 255], 1);
        eidx[pos] = p & 0x1FFFF;
    }
}

// ---------------------------------------------------------------------------
// Pass D (src): per-bucket byte histogram -> ninv_out
// ---------------------------------------------------------------------------
__global__ __launch_bounds__(256)
void buildDsrc_kernel(const unsigned char* __restrict__ sbytes, const int* __restrict__ bbs,
                      float* __restrict__ ninv_out, int N) {
    __shared__ int cnt[256];
    int b = blockIdx.x, tid = threadIdx.x;
    int beg = bbs[b], end = bbs[b + 1];
    cnt[tid] = 0;
    __syncthreads();
    for (int i = beg + tid; i < end; i += 256)
        atomicAdd(&cnt[sbytes[i]], 1);
    __syncthreads();
    int node = (b << NB_SHIFT) + tid;
    if (node < N) {
        int v = cnt[tid];
        ninv_out[node] = (v > 0) ? rsqrtf((float)v) : 0.0f;
    }
}

// ---------------------------------------------------------------------------
// conv: xb = bf16(in_feat * ninv_out)
// ---------------------------------------------------------------------------
__global__ __launch_bounds__(256)
void conv_kernel(const float* __restrict__ in_feat, const float* __restrict__ ninv_out,
                 unsigned int* __restrict__ xb, int N) {
    int gid = blockIdx.x * 256 + threadIdx.x;   // [0, N*32)
    if (gid >= N * 32) return;
    int r = gid >> 5, q = gid & 31;
    float no = ninv_out[r];
    float4 v = ((const float4*)in_feat)[(long)r * 32 + q];
    uint2 o;
    o.x = pack2(v.x * no, v.y * no);
    o.y = pack2(v.z * no, v.w * no);
    ((uint2*)xb)[(long)r * 32 + q] = o;
}

// ---------------------------------------------------------------------------
// Layer-1 aggregation: one WAVE per node, lane owns one uint (2 bf16).
// ---------------------------------------------------------------------------
__global__ __launch_bounds__(256)
void agg1_kernel(const unsigned int* __restrict__ xb, const int* __restrict__ row_ptr,
                 const int* __restrict__ eidx, unsigned int* __restrict__ Bb, int N) {
    int wave = threadIdx.x >> 6;
    int lane = threadIdx.x & 63;
    int d = blockIdx.x * 4 + wave;
    if (d >= N) return;
    int beg = row_ptr[d], end = row_ptr[d + 1];
    float ax = 0.f, ay = 0.f;
    int j = beg;
    for (; j + 8 <= end; j += 8) {
        int s0 = eidx[j+0], s1 = eidx[j+1], s2 = eidx[j+2], s3 = eidx[j+3];
        int s4 = eidx[j+4], s5 = eidx[j+5], s6 = eidx[j+6], s7 = eidx[j+7];
        unsigned int u0 = xb[(long)s0*64+lane], u1 = xb[(long)s1*64+lane];
        unsigned int u2 = xb[(long)s2*64+lane], u3 = xb[(long)s3*64+lane];
        unsigned int u4 = xb[(long)s4*64+lane], u5 = xb[(long)s5*64+lane];
        unsigned int u6 = xb[(long)s6*64+lane], u7 = xb[(long)s7*64+lane];
        ax += lo_f(u0) + lo_f(u1) + lo_f(u2) + lo_f(u3)
            + lo_f(u4) + lo_f(u5) + lo_f(u6) + lo_f(u7);
        ay += hi_f(u0) + hi_f(u1) + hi_f(u2) + hi_f(u3)
            + hi_f(u4) + hi_f(u5) + hi_f(u6) + hi_f(u7);
    }
    for (; j + 2 <= end; j += 2) {
        unsigned int u0 = xb[(long)eidx[j]*64+lane], u1 = xb[(long)eidx[j+1]*64+lane];
        ax += lo_f(u0) + lo_f(u1);
        ay += hi_f(u0) + hi_f(u1);
    }
    if (j < end) {
        unsigned int u = xb[(long)eidx[j]*64+lane];
        ax += lo_f(u); ay += hi_f(u);
    }
    Bb[(long)d * 64 + lane] = pack2(ax, ay);
}

// ---------------------------------------------------------------------------
// Fused mm1+mm2 via MFMA (bf16 in, f32 accum):
//   t[row] = ninv_out[row] * (relu(B[row]@W1 * ninv_in + b1) @ W2)
// Block: 256 thr = 4 waves; tile 64 rows; wave owns 16 rows x 128 cols.
// W1 staged bf16-transposed in LDS [c][k2] stride 68 (16B-aligned rows).
// A-frags: uint4 direct from global Bb. C/D: col=lane&15, row=(lane>>4)*4+reg.
// ---------------------------------------------------------------------------
#define MM_ROWS 64
__global__ __launch_bounds__(256)
void mm1_kernel(const unsigned int* __restrict__ Bb, const float* __restrict__ W1,
                const float* __restrict__ b1, const float* __restrict__ ninv_in,
                const float* __restrict__ ninv_out, const float* __restrict__ W2,
                float* __restrict__ t, int N) {
    __shared__ unsigned int w1t[128 * 68];    // [c][k2], k2=k/2, padded to 68
    int tid = threadIdx.x;
    int wave = tid >> 6, lane = tid & 63;
    int row0 = blockIdx.x * MM_ROWS;

    // stage W1 -> bf16 transposed LDS: thread handles c = tid&127, kh = tid>>7
    {
        int c = tid & 127;
        int kh = tid >> 7;
#pragma unroll 8
        for (int j = 0; j < 32; ++j) {
            int k2 = j * 2 + kh;              // 0..63
            float a = W1[(k2 * 2)     * HID + c];
            float b = W1[(k2 * 2 + 1) * HID + c];
            w1t[c * 68 + k2] = pack2(a, b);
        }
    }

    // per-lane epilogue constants: cols n = (lane&15) + 16*ct
    int m = lane & 15;
    int kg = lane >> 4;                        // 0..3
    float  b1r[8];
    float2 w2r[8];
    const float2* W2v = (const float2*)W2;
#pragma unroll
    for (int ct = 0; ct < 8; ++ct) {
        int n = m + 16 * ct;
        b1r[ct] = b1[n];
        w2r[ct] = W2v[n];
    }

    // A-fragments: row r, k in [ks*32 + kg*8, +8)  -> uint4 at Bb[r*64+ks*16+kg*4]
    int r = row0 + wave * 16 + m;
    U8 afrag[4];
    if (r < N) {
#pragma unroll
        for (int ks = 0; ks < 4; ++ks)
            afrag[ks].u = *(const uint4*)&Bb[(long)r * 64 + ks * 16 + kg * 4];
    } else {
#pragma unroll
        for (int ks = 0; ks < 4; ++ks)
            afrag[ks].u = make_uint4(0u, 0u, 0u, 0u);
    }
    __syncthreads();

    f32x4 acc[8];
#pragma unroll
    for (int ct = 0; ct < 8; ++ct) acc[ct] = (f32x4){0.f, 0.f, 0.f, 0.f};

#pragma unroll
    for (int ks = 0; ks < 4; ++ks) {
#pragma unroll
        for (int ct = 0; ct < 8; ++ct) {
            U8 bf;
            bf.u = *(const uint4*)&w1t[(m + 16 * ct) * 68 + ks * 16 + kg * 4];
            acc[ct] = __builtin_amdgcn_mfma_f32_16x16x32_bf16(afrag[ks].v, bf.v, acc[ct], 0, 0, 0);
        }
    }

    // epilogue: rows of this quarter-group q = kg: grow = row0+wave*16+kg*4+reg
#pragma unroll
    for (int reg = 0; reg < 4; ++reg) {
        int grow = row0 + wave * 16 + kg * 4 + reg;
        int cg = min(grow, N - 1);
        float ni = ninv_in[cg];
        float p0 = 0.f, p1 = 0.f;
#pragma unroll
        for (int ct = 0; ct < 8; ++ct) {
            float h = fmaxf(acc[ct][reg] * ni + b1r[ct], 0.f);
            p0 += h * w2r[ct].x;
            p1 += h * w2r[ct].y;
        }
#pragma unroll
        for (int off = 8; off >= 1; off >>= 1) {
            p0 += __shfl_xor(p0, off, 16);
            p1 += __shfl_xor(p1, off, 16);
        }
        if (m == 0 && grow < N) {
            float no = ninv_out[grow];
            ((float2*)t)[grow] = make_float2(p0 * no, p1 * no);
        }
    }
}

// ---------------------------------------------------------------------------
// Layer-2 CSR gather fused with epilogue
// ---------------------------------------------------------------------------
__global__ void final2_kernel(const float* __restrict__ t, const int* __restrict__ row_ptr,
                              const int* __restrict__ eidx, const float* __restrict__ ninv_in,
                              const float* __restrict__ b2, float* __restrict__ out, int N) {
    int i = blockIdx.x * blockDim.x + threadIdx.x;
    if (i >= N) return;
    int beg = row_ptr[i], end = row_ptr[i + 1];
    const float2* t2 = (const float2*)t;
    float ax = 0.f, ay = 0.f;
    int j = beg;
    for (; j + 4 <= end; j += 4) {
        float2 v0 = t2[eidx[j]], v1 = t2[eidx[j+1]], v2 = t2[eidx[j+2]], v3 = t2[eidx[j+3]];
        ax += v0.x + v1.x + v2.x + v3.x;
        ay += v0.y + v1.y + v2.y + v3.y;
    }
    for (; j < end; ++j) {
        float2 v = t2[eidx[j]];
        ax += v.x; ay += v.y;
    }
    float ni = ninv_in[i];
    float2 o;
    o.x = ax * ni + b2[0];
    o.y = ay * ni + b2[1];
    ((float2*)out)[i] = o;
}

// ---------------------------------------------------------------------------
extern "C" void kernel_launch(void* const* d_in, const int* in_sizes, int n_in,
                              void* d_out, int out_size, void* d_ws, size_t ws_size,
                              hipStream_t stream) {
    const float* in_feat = (const float*)d_in[0];
    const float* W1      = (const float*)d_in[1];
    const float* b1      = (const float*)d_in[2];
    const float* W2      = (const float*)d_in[3];
    const float* b2      = (const float*)d_in[4];
    const int*   src     = (const int*)d_in[5];
    const int*   dst     = (const int*)d_in[6];
    int N = in_sizes[0] / IN_F;
    int E = in_sizes[5];
    int NB = (N + 255) >> 8;

    unsigned int* Bb  = (unsigned int*)d_ws;
    int*   pairs      = (int*)Bb;                            // E ints (consumed pre-agg1)
    unsigned char* sbytes = (unsigned char*)(Bb + E);        // E bytes (consumed pre-agg1)
    unsigned int* xb  = Bb + (size_t)64 * N;
    float* ninv_out   = (float*)(xb + (size_t)64 * N);       // N
    float* ninv_in    = ninv_out + N;                        // N
    float* t          = ninv_in + N;                         // 2N
    int*   row_ptr    = (int*)(t + (size_t)2 * N);           // N+1
    int*   eidx       = row_ptr + N + 1;                     // E
    int*   cd         = eidx + E;                            // NCHUNK*NBKT
    int*   cs         = cd + NCHUNK * NBKT;                  // NCHUNK*NBKT
    int*   btd        = cs + NCHUNK * NBKT;                  // 512
    int*   bts        = btd + NBKT;                          // 512
    int*   bbd        = bts + NBKT;                          // 513
    int*   bbs        = bbd + NBKT + 1;                      // 513

    int epc = (E + NCHUNK - 1) / NCHUNK;

    countAB_kernel<<<NCHUNK, 256, 0, stream>>>(src, dst, cd, cs, E, epc);
    scanB1_kernel<<<2 * NBKT, 256, 0, stream>>>(cd, cs, btd, bts);
    scanB2_kernel<<<2, 512, 0, stream>>>(btd, bts, bbd, bbs, row_ptr, N, E);
    scatterAB_kernel<<<NCHUNK, 256, 0, stream>>>(src, dst, cd, cs, bbd, bbs,
                                                 pairs, sbytes, E, epc);
    buildD_kernel<<<NB, 256, 0, stream>>>(pairs, bbd, row_ptr, ninv_in, eidx, N);
    buildDsrc_kernel<<<NB, 256, 0, stream>>>(sbytes, bbs, ninv_out, N);

    conv_kernel<<<(N * 32 + 255) / 256, 256, 0, stream>>>(in_feat, ninv_out, xb, N);

    agg1_kernel<<<(N + 3) / 4, 256, 0, stream>>>(xb, row_ptr, eidx, Bb, N);

    mm1_kernel<<<(N + MM_ROWS - 1) / MM_ROWS, 256, 0, stream>>>(
        Bb, W1, b1, ninv_in, ninv_out, W2, t, N);

    final2_kernel<<<(N + 255) / 256, 256, 0, stream>>>(
        t, row_ptr, eidx, ninv_in, b2, (float*)d_out, N);
}

// Round 7
// 257.216 us; speedup vs baseline: 12.3044x; 1.0052x over previous
//
#include <hip/hip_runtime.h>

#define IN_F 128
#define HID  128
#define NB_SHIFT 8        // 256 nodes per bucket
#define NBKT 512          // padded bucket count (real NB = ceil(N/256) = 391)
#define NCHUNK 256        // edge chunks for count/scatter passes

typedef __bf16 bf16x8 __attribute__((ext_vector_type(8)));
typedef float f32x4 __attribute__((ext_vector_type(4)));
union U8 { uint4 u; bf16x8 v; };

// ---- bf16 helpers (RNE pack, shift-unpack) --------------------------------
__device__ __forceinline__ unsigned int bfround(float x) {
    unsigned int u = __float_as_uint(x);
    return (u + 0x7fffu + ((u >> 16) & 1u)) >> 16;
}
__device__ __forceinline__ unsigned int pack2(float a, float b) {
    return bfround(a) | (bfround(b) << 16);
}
__device__ __forceinline__ float lo_f(unsigned int u) { return __uint_as_float(u << 16); }
__device__ __forceinline__ float hi_f(unsigned int u) { return __uint_as_float(u & 0xffff0000u); }

// ---------------------------------------------------------------------------
// Pass A: per-chunk histograms of BOTH src and dst buckets (LDS atomics)
// ---------------------------------------------------------------------------
__global__ __launch_bounds__(256)
void countAB_kernel(const int* __restrict__ src, const int* __restrict__ dst,
                    int* __restrict__ cd, int* __restrict__ cs, int E, int epc) {
    __shared__ int hd[NBKT], hs[NBKT];
    int tid = threadIdx.x, c = blockIdx.x;
    hd[tid] = 0; hd[tid + 256] = 0; hs[tid] = 0; hs[tid + 256] = 0;
    __syncthreads();
    int lo = c * epc, hi = min(lo + epc, E);
    for (int i = lo + tid; i < hi; i += 256) {
        atomicAdd(&hd[dst[i] >> NB_SHIFT], 1);
        atomicAdd(&hs[src[i] >> NB_SHIFT], 1);
    }
    __syncthreads();
    cd[c * NBKT + tid] = hd[tid]; cd[c * NBKT + tid + 256] = hd[tid + 256];
    cs[c * NBKT + tid] = hs[tid]; cs[c * NBKT + tid + 256] = hs[tid + 256];
}

// ---------------------------------------------------------------------------
// Pass B1: per-bucket exclusive scan over chunks (in place), bucket totals out
// ---------------------------------------------------------------------------
__global__ __launch_bounds__(256)
void scanB1_kernel(int* __restrict__ cd, int* __restrict__ cs,
                   int* __restrict__ btd, int* __restrict__ bts) {
    __shared__ int sd[256];
    int b = blockIdx.x, tid = threadIdx.x;
    int* arr = (b < NBKT) ? cd : cs;
    int* bt  = (b < NBKT) ? btd : bts;
    int col = b & (NBKT - 1);
    int v = arr[tid * NBKT + col];
    sd[tid] = v; __syncthreads();
    for (int off = 1; off < 256; off <<= 1) {
        int t = (tid >= off) ? sd[tid - off] : 0;
        __syncthreads();
        sd[tid] += t;
        __syncthreads();
    }
    arr[tid * NBKT + col] = sd[tid] - v;
    if (tid == 255) bt[col] = sd[255];
}

// ---------------------------------------------------------------------------
// Pass B2: blocks 0,1 = exclusive scans of bucket totals (dst, src);
// blocks 2..17 = pack W1 -> bf16-transposed w1tb [c][k2] (independent work)
// ---------------------------------------------------------------------------
__global__ __launch_bounds__(512)
void scanB2_kernel(const int* __restrict__ btd, const int* __restrict__ bts,
                   int* __restrict__ bbd, int* __restrict__ bbs,
                   int* __restrict__ row_ptr, const float* __restrict__ W1,
                   unsigned int* __restrict__ w1tb, int N, int E) {
    int tid = threadIdx.x;
    if (blockIdx.x >= 2) {
        // pack W1: idx in [0, 8192); c = idx&127 (coalesced reads), k2 = idx>>7
        int idx = (blockIdx.x - 2) * 512 + tid;
        int c = idx & 127, k2 = idx >> 7;
        float a = W1[(2 * k2)     * HID + c];
        float b = W1[(2 * k2 + 1) * HID + c];
        w1tb[c * 64 + k2] = pack2(a, b);
        return;
    }
    __shared__ int sd[512];
    const int* bt = blockIdx.x ? bts : btd;
    int* bb = blockIdx.x ? bbs : bbd;
    int v = bt[tid];
    sd[tid] = v; __syncthreads();
    for (int off = 1; off < 512; off <<= 1) {
        int t = (tid >= off) ? sd[tid - off] : 0;
        __syncthreads();
        sd[tid] += t;
        __syncthreads();
    }
    bb[tid] = sd[tid] - v;
    if (tid == 511) bb[512] = sd[511];  // == E
    if (blockIdx.x == 0 && tid == 0) row_ptr[N] = E;
}

// ---------------------------------------------------------------------------
// Pass C: scatter packed dst-pairs + src low-bytes (LDS cursors)
// ---------------------------------------------------------------------------
__global__ __launch_bounds__(256)
void scatterAB_kernel(const int* __restrict__ src, const int* __restrict__ dst,
                      const int* __restrict__ cd, const int* __restrict__ cs,
                      const int* __restrict__ bbd, const int* __restrict__ bbs,
                      int* __restrict__ pairs, unsigned char* __restrict__ sbytes,
                      int E, int epc) {
    __shared__ int curd[NBKT], curs[NBKT];
    int tid = threadIdx.x, c = blockIdx.x;
    curd[tid]       = cd[c * NBKT + tid]       + bbd[tid];
    curd[tid + 256] = cd[c * NBKT + tid + 256] + bbd[tid + 256];
    curs[tid]       = cs[c * NBKT + tid]       + bbs[tid];
    curs[tid + 256] = cs[c * NBKT + tid + 256] + bbs[tid + 256];
    __syncthreads();
    int lo = c * epc, hi = min(lo + epc, E);
    for (int i = lo + tid; i < hi; i += 256) {
        int s = src[i], d = dst[i];
        int pd = atomicAdd(&curd[d >> NB_SHIFT], 1);
        pairs[pd] = s | ((d & 255) << 17);          // src < 2^17
        int ps = atomicAdd(&curs[s >> NB_SHIFT], 1);
        sbytes[ps] = (unsigned char)(s & 255);
    }
}

// ---------------------------------------------------------------------------
// Pass D fused: blocks [0,NB) = dst counting sort -> row_ptr, ninv_in, eidx;
// blocks [NB,2NB) = src byte histogram -> ninv_out
// ---------------------------------------------------------------------------
__global__ __launch_bounds__(256)
void buildD2_kernel(const int* __restrict__ pairs, const unsigned char* __restrict__ sbytes,
                    const int* __restrict__ bbd, const int* __restrict__ bbs,
                    int* __restrict__ row_ptr, float* __restrict__ ninv_in,
                    float* __restrict__ ninv_out, int* __restrict__ eidx,
                    int N, int NB) {
    __shared__ int cnt[256], sd[256], cursor[256];
    int tid = threadIdx.x;
    if (blockIdx.x >= NB) {
        // ---- src role: byte histogram -> ninv_out
        int b = blockIdx.x - NB;
        int beg = bbs[b], end = bbs[b + 1];
        cnt[tid] = 0;
        __syncthreads();
        for (int i = beg + tid; i < end; i += 256)
            atomicAdd(&cnt[sbytes[i]], 1);
        __syncthreads();
        int node = (b << NB_SHIFT) + tid;
        if (node < N) {
            int v = cnt[tid];
            ninv_out[node] = (v > 0) ? rsqrtf((float)v) : 0.0f;
        }
        return;
    }
    // ---- dst role: counting sort
    int b = blockIdx.x;
    int beg = bbd[b], end = bbd[b + 1];
    cnt[tid] = 0;
    __syncthreads();
    for (int i = beg + tid; i < end; i += 256)
        atomicAdd(&cnt[(pairs[i] >> 17) & 255], 1);
    __syncthreads();
    int v = cnt[tid];
    sd[tid] = v; __syncthreads();
    for (int off = 1; off < 256; off <<= 1) {
        int t = (tid >= off) ? sd[tid - off] : 0;
        __syncthreads();
        sd[tid] += t;
        __syncthreads();
    }
    int excl = sd[tid] - v;
    int node = (b << NB_SHIFT) + tid;
    if (node < N) {
        row_ptr[node] = beg + excl;
        ninv_in[node] = (v > 0) ? rsqrtf((float)v) : 0.0f;
    }
    cursor[tid] = beg + excl;
    __syncthreads();
    for (int i = beg + tid; i < end; i += 256) {
        int p = pairs[i];
        int pos = atomicAdd(&cursor[(p >> 17) & 255], 1);
        eidx[pos] = p & 0x1FFFF;
    }
}

// ---------------------------------------------------------------------------
// conv: xb = bf16(in_feat * ninv_out)
// ---------------------------------------------------------------------------
__global__ __launch_bounds__(256)
void conv_kernel(const float* __restrict__ in_feat, const float* __restrict__ ninv_out,
                 unsigned int* __restrict__ xb, int N) {
    int gid = blockIdx.x * 256 + threadIdx.x;   // [0, N*32)
    if (gid >= N * 32) return;
    int r = gid >> 5, q = gid & 31;
    float no = ninv_out[r];
    float4 v = ((const float4*)in_feat)[(long)r * 32 + q];
    uint2 o;
    o.x = pack2(v.x * no, v.y * no);
    o.y = pack2(v.z * no, v.w * no);
    ((uint2*)xb)[(long)r * 32 + q] = o;
}

// ---------------------------------------------------------------------------
// Layer-1 aggregation: one WAVE per node. Lane half 0 (lanes 0-31) owns uint2
// slot hl of EVEN edges, half 1 of ODD edges -> each gather instruction
// covers 2 edges (512B), halving vmem instruction count. 16 edges in flight.
// ---------------------------------------------------------------------------
__global__ __launch_bounds__(256)
void agg1_kernel(const unsigned int* __restrict__ xb, const int* __restrict__ row_ptr,
                 const int* __restrict__ eidx, unsigned int* __restrict__ Bb, int N) {
    int wave = threadIdx.x >> 6;
    int lane = threadIdx.x & 63;
    int half = lane >> 5;           // which edge parity this lane covers
    int hl   = lane & 31;           // uint2 slot within the 128-f row
    int d = blockIdx.x * 4 + wave;
    if (d >= N) return;
    int beg = row_ptr[d], end = row_ptr[d + 1];
    const uint2* x2 = (const uint2*)xb;     // row = 32 uint2
    float ax = 0.f, ay = 0.f, az = 0.f, aw = 0.f;
    int j = beg;
    for (; j + 16 <= end; j += 16) {
        int e0 = eidx[j +  0 + half], e1 = eidx[j +  2 + half];
        int e2 = eidx[j +  4 + half], e3 = eidx[j +  6 + half];
        int e4 = eidx[j +  8 + half], e5 = eidx[j + 10 + half];
        int e6 = eidx[j + 12 + half], e7 = eidx[j + 14 + half];
        uint2 u0 = x2[(long)e0*32 + hl], u1 = x2[(long)e1*32 + hl];
        uint2 u2 = x2[(long)e2*32 + hl], u3 = x2[(long)e3*32 + hl];
        uint2 u4 = x2[(long)e4*32 + hl], u5 = x2[(long)e5*32 + hl];
        uint2 u6 = x2[(long)e6*32 + hl], u7 = x2[(long)e7*32 + hl];
        ax += lo_f(u0.x) + lo_f(u1.x) + lo_f(u2.x) + lo_f(u3.x)
            + lo_f(u4.x) + lo_f(u5.x) + lo_f(u6.x) + lo_f(u7.x);
        ay += hi_f(u0.x) + hi_f(u1.x) + hi_f(u2.x) + hi_f(u3.x)
            + hi_f(u4.x) + hi_f(u5.x) + hi_f(u6.x) + hi_f(u7.x);
        az += lo_f(u0.y) + lo_f(u1.y) + lo_f(u2.y) + lo_f(u3.y)
            + lo_f(u4.y) + lo_f(u5.y) + lo_f(u6.y) + lo_f(u7.y);
        aw += hi_f(u0.y) + hi_f(u1.y) + hi_f(u2.y) + hi_f(u3.y)
            + hi_f(u4.y) + hi_f(u5.y) + hi_f(u6.y) + hi_f(u7.y);
    }
    for (; j + 2 <= end; j += 2) {
        int e = eidx[j + half];
        uint2 u = x2[(long)e*32 + hl];
        ax += lo_f(u.x); ay += hi_f(u.x); az += lo_f(u.y); aw += hi_f(u.y);
    }
    if (j < end && half == 0) {     // odd leftover edge: half 0 only
        int e = eidx[j];
        uint2 u = x2[(long)e*32 + hl];
        ax += lo_f(u.x); ay += hi_f(u.x); az += lo_f(u.y); aw += hi_f(u.y);
    }
    // merge the two edge-parity halves (lane L += lane L+32)
    ax += __shfl_xor(ax, 32); ay += __shfl_xor(ay, 32);
    az += __shfl_xor(az, 32); aw += __shfl_xor(aw, 32);
    if (half == 0) {
        uint2 o;
        o.x = pack2(ax, ay);
        o.y = pack2(az, aw);
        ((uint2*)Bb)[(long)d * 32 + hl] = o;
    }
}

// ---------------------------------------------------------------------------
// Fused mm1+mm2 via MFMA (bf16 in, f32 accum):
//   t[row] = ninv_out[row] * (relu(B[row]@W1 * ninv_in + b1) @ W2)
// W1 comes prepacked bf16-transposed from global w1tb (coalesced uint4 stage).
// ---------------------------------------------------------------------------
#define MM_ROWS 64
__global__ __launch_bounds__(256)
void mm1_kernel(const unsigned int* __restrict__ Bb, const unsigned int* __restrict__ w1tb,
                const float* __restrict__ b1, const float* __restrict__ ninv_in,
                const float* __restrict__ ninv_out, const float* __restrict__ W2,
                float* __restrict__ t, int N) {
    __shared__ unsigned int w1t[128 * 68];    // [c][k2], padded stride 68
    int tid = threadIdx.x;
    int wave = tid >> 6, lane = tid & 63;
    int row0 = blockIdx.x * MM_ROWS;

    // stage prepacked W1: 2048 uint4, coalesced global -> padded LDS
    {
        const uint4* g = (const uint4*)w1tb;
#pragma unroll
        for (int pass = 0; pass < 8; ++pass) {
            int idx = pass * 256 + tid;       // uint4 index
            int c = idx >> 4, q = idx & 15;
            *(uint4*)&w1t[c * 68 + q * 4] = g[idx];
        }
    }

    // per-lane epilogue constants: cols n = (lane&15) + 16*ct
    int m = lane & 15;
    int kg = lane >> 4;                        // 0..3
    float  b1r[8];
    float2 w2r[8];
    const float2* W2v = (const float2*)W2;
#pragma unroll
    for (int ct = 0; ct < 8; ++ct) {
        int n = m + 16 * ct;
        b1r[ct] = b1[n];
        w2r[ct] = W2v[n];
    }

    // A-fragments: row r, k in [ks*32 + kg*8, +8)  -> uint4 at Bb[r*64+ks*16+kg*4]
    int r = row0 + wave * 16 + m;
    U8 afrag[4];
    if (r < N) {
#pragma unroll
        for (int ks = 0; ks < 4; ++ks)
            afrag[ks].u = *(const uint4*)&Bb[(long)r * 64 + ks * 16 + kg * 4];
    } else {
#pragma unroll
        for (int ks = 0; ks < 4; ++ks)
            afrag[ks].u = make_uint4(0u, 0u, 0u, 0u);
    }
    __syncthreads();

    f32x4 acc[8];
#pragma unroll
    for (int ct = 0; ct < 8; ++ct) acc[ct] = (f32x4){0.f, 0.f, 0.f, 0.f};

#pragma unroll
    for (int ks = 0; ks < 4; ++ks) {
#pragma unroll
        for (int ct = 0; ct < 8; ++ct) {
            U8 bf;
            bf.u = *(const uint4*)&w1t[(m + 16 * ct) * 68 + ks * 16 + kg * 4];
            acc[ct] = __builtin_amdgcn_mfma_f32_16x16x32_bf16(afrag[ks].v, bf.v, acc[ct], 0, 0, 0);
        }
    }

    // epilogue: rows of quarter-group kg: grow = row0 + wave*16 + kg*4 + reg
#pragma unroll
    for (int reg = 0; reg < 4; ++reg) {
        int grow = row0 + wave * 16 + kg * 4 + reg;
        int cg = min(grow, N - 1);
        float ni = ninv_in[cg];
        float p0 = 0.f, p1 = 0.f;
#pragma unroll
        for (int ct = 0; ct < 8; ++ct) {
            float h = fmaxf(acc[ct][reg] * ni + b1r[ct], 0.f);
            p0 += h * w2r[ct].x;
            p1 += h * w2r[ct].y;
        }
#pragma unroll
        for (int off = 8; off >= 1; off >>= 1) {
            p0 += __shfl_xor(p0, off, 16);
            p1 += __shfl_xor(p1, off, 16);
        }
        if (m == 0 && grow < N) {
            float no = ninv_out[grow];
            ((float2*)t)[grow] = make_float2(p0 * no, p1 * no);
        }
    }
}

// ---------------------------------------------------------------------------
// Layer-2 CSR gather fused with epilogue
// ---------------------------------------------------------------------------
__global__ void final2_kernel(const float* __restrict__ t, const int* __restrict__ row_ptr,
                              const int* __restrict__ eidx, const float* __restrict__ ninv_in,
                              const float* __restrict__ b2, float* __restrict__ out, int N) {
    int i = blockIdx.x * blockDim.x + threadIdx.x;
    if (i >= N) return;
    int beg = row_ptr[i], end = row_ptr[i + 1];
    const float2* t2 = (const float2*)t;
    float ax = 0.f, ay = 0.f;
    int j = beg;
    for (; j + 4 <= end; j += 4) {
        float2 v0 = t2[eidx[j]], v1 = t2[eidx[j+1]], v2 = t2[eidx[j+2]], v3 = t2[eidx[j+3]];
        ax += v0.x + v1.x + v2.x + v3.x;
        ay += v0.y + v1.y + v2.y + v3.y;
    }
    for (; j < end; ++j) {
        float2 v = t2[eidx[j]];
        ax += v.x; ay += v.y;
    }
    float ni = ninv_in[i];
    float2 o;
    o.x = ax * ni + b2[0];
    o.y = ay * ni + b2[1];
    ((float2*)out)[i] = o;
}

// ---------------------------------------------------------------------------
extern "C" void kernel_launch(void* const* d_in, const int* in_sizes, int n_in,
                              void* d_out, int out_size, void* d_ws, size_t ws_size,
                              hipStream_t stream) {
    const float* in_feat = (const float*)d_in[0];
    const float* W1      = (const float*)d_in[1];
    const float* b1      = (const float*)d_in[2];
    const float* W2      = (const float*)d_in[3];
    const float* b2      = (const float*)d_in[4];
    const int*   src     = (const int*)d_in[5];
    const int*   dst     = (const int*)d_in[6];
    int N = in_sizes[0] / IN_F;
    int E = in_sizes[5];
    int NB = (N + 255) >> 8;

    unsigned int* Bb  = (unsigned int*)d_ws;
    int*   pairs      = (int*)Bb;                            // E ints (consumed pre-agg1)
    unsigned char* sbytes = (unsigned char*)(Bb + E);        // E bytes (consumed pre-agg1)
    unsigned int* xb  = Bb + (size_t)64 * N;
    float* ninv_out   = (float*)(xb + (size_t)64 * N);       // N
    float* ninv_in    = ninv_out + N;                        // N
    float* t          = ninv_in + N;                         // 2N
    int*   row_ptr    = (int*)(t + (size_t)2 * N);           // N+1
    int*   eidx       = row_ptr + N + 1;                     // E
    int*   cd         = eidx + E;                            // NCHUNK*NBKT
    int*   cs         = cd + NCHUNK * NBKT;                  // NCHUNK*NBKT
    int*   btd        = cs + NCHUNK * NBKT;                  // 512
    int*   bts        = btd + NBKT;                          // 512
    int*   bbd        = bts + NBKT;                          // 513
    int*   bbs        = bbd + NBKT + 1;                      // 513
    unsigned int* w1tb = (unsigned int*)(bbs + NBKT + 1);    // 8192 uints (32KB)

    int epc = (E + NCHUNK - 1) / NCHUNK;

    countAB_kernel<<<NCHUNK, 256, 0, stream>>>(src, dst, cd, cs, E, epc);
    scanB1_kernel<<<2 * NBKT, 256, 0, stream>>>(cd, cs, btd, bts);
    scanB2_kernel<<<18, 512, 0, stream>>>(btd, bts, bbd, bbs, row_ptr, W1, w1tb, N, E);
    scatterAB_kernel<<<NCHUNK, 256, 0, stream>>>(src, dst, cd, cs, bbd, bbs,
                                                 pairs, sbytes, E, epc);
    buildD2_kernel<<<2 * NB, 256, 0, stream>>>(pairs, sbytes, bbd, bbs,
                                               row_ptr, ninv_in, ninv_out, eidx, N, NB);

    conv_kernel<<<(N * 32 + 255) / 256, 256, 0, stream>>>(in_feat, ninv_out, xb, N);

    agg1_kernel<<<(N + 3) / 4, 256, 0, stream>>>(xb, row_ptr, eidx, Bb, N);

    mm1_kernel<<<(N + MM_ROWS - 1) / MM_ROWS, 256, 0, stream>>>(
        Bb, w1tb, b1, ninv_in, ninv_out, W2, t, N);

    final2_kernel<<<(N + 255) / 256, 256, 0, stream>>>(
        t, row_ptr, eidx, ninv_in, b2, (float*)d_out, N);
}